// Round 8
// baseline (872.499 us; speedup 1.0000x reference)
//
#include <hip/hip_runtime.h>

#define NN 100000
#define NE 1600000
#define HID 64
#define EPSV 1e-5f
#define NB_ATT 256

// bucketed CSR build
#define NBUK 391                 // ceil(NN/256), bucket = dst>>8
#define BCAP 4608                // slots per bucket (lambda~4092, +8 sigma)
#define BTILE 4096               // edges per bin tile
#define NTILES 391               // ceil(NE/BTILE)
#define NB_BUILD 391             // build grid (== NTILES == NBUK, all resident)

// ---------- small scratch layout (float indices into ws) ----------
#define SM_SUMS(l)  ((l)*128)
#define SM_SUMSQ(l) ((l)*128 + 64)
#define SM_HS       512
#define SM_C        576
#define SM_HV       768          // 64 floats
#define SM_EOFF     832
#define SM_BAR      960          // 4 ints: (cnt,flag) x2
#define SM_GCUR     1024         // 392 ints (zeroed by memset)
#define SM_ZEND     1424         // memset covers [0, SM_ZEND)

// big buffers (float offsets)
#define NPAD        100352L
#define OFF_DINV    1424L
#define OFF_H       (OFF_DINV + NPAD)       // 6.4M floats; stage AND hb alias this region
#define OFF_Y32     (OFF_H + 6400000L)      // 3.2M uints (bf16x2)
#define OFF_PART    (OFF_Y32 + 3200000L)    // NB_ATT*68
#define OFF_INT     (OFF_PART + 69632L)

static __device__ __forceinline__ unsigned bf16rne(float f) {
  unsigned u = __float_as_uint(f);
  return (u + 0x7fffu + ((u >> 16) & 1u)) >> 16;
}
static __device__ __forceinline__ unsigned packbf2(float lo, float hi) {
  return bf16rne(lo) | (bf16rne(hi) << 16);
}
static __device__ __forceinline__ float bflo(unsigned w) { return __uint_as_float(w << 16); }
static __device__ __forceinline__ float bfhi(unsigned w) { return __uint_as_float(w & 0xffff0000u); }

// GraphNorm affine from accumulated sums: gn(x) = sc*x + sh  (per feature j)
static __device__ __forceinline__ void gn_affine(int j, const float* w, const float* b,
                                                 const float* ms, const float* sums,
                                                 const float* sumsq, float& sc, float& sh) {
  const float invn = 1.0f / (float)NN;
  float mean = sums[j] * invn;
  float ex2  = sumsq[j] * invn;
  float m    = ms[j];
  float var  = ex2 - m * mean * mean * (2.0f - m);
  sc = w[j] * rsqrtf(var + EPSV);
  sh = b[j] - sc * m * mean;
}

// ---------------- device-scope grid barrier (load-polling, self-resetting) ----------------
// Waiters poll with agent-scope atomic LOADS (no RMW -> no exclusive-ownership ping-pong);
// release is one release-ordered fetch_add. Round-7's RMW-polling cost ~30-100us/barrier.
static __device__ __forceinline__ void gridbar(int* cnt, unsigned* flag, int nb) {
  __syncthreads();
  __threadfence();
  if (threadIdx.x == 0) {
    unsigned gen = __hip_atomic_load(flag, __ATOMIC_RELAXED, __HIP_MEMORY_SCOPE_AGENT);
    if (atomicAdd(cnt, 1) == nb - 1) {
      atomicExch(cnt, 0);
      __hip_atomic_fetch_add(flag, 1u, __ATOMIC_RELEASE, __HIP_MEMORY_SCOPE_AGENT);
    } else {
      while (__hip_atomic_load(flag, __ATOMIC_RELAXED, __HIP_MEMORY_SCOPE_AGENT) == gen)
        __builtin_amdgcn_s_sleep(8);
    }
  }
  __syncthreads();
  __threadfence();
}

// ---------------- fused CSR build + gn0 stats (persistent, 2 grid barriers) ----------------
__global__ __launch_bounds__(256, 4) void k_build(const int* __restrict__ src, const int* __restrict__ dst,
                                                  const float* __restrict__ x,
                                                  int* __restrict__ gcursor, unsigned* __restrict__ stage,
                                                  int* __restrict__ boff,
                                                  int* __restrict__ col, int* __restrict__ rowptr,
                                                  float* __restrict__ dinv,
                                                  float* __restrict__ sums0, float* __restrict__ sumsq0,
                                                  int* __restrict__ barc, unsigned* __restrict__ barf) {
  __shared__ int hist[NBUK], base[NBUK];
  __shared__ int hist256[256], cur256[256];
  __shared__ int ws[8];
  int t = threadIdx.x, lane = t & 63;

  // ---- phase A1: bin edges into per-bucket staging (1 tile of 4096 per block) ----
  for (int tile = blockIdx.x; tile < NTILES; tile += gridDim.x) {
    __syncthreads();
    for (int b = t; b < NBUK; b += 256) hist[b] = 0;
    __syncthreads();
    long e0 = (long)tile * BTILE;
    unsigned v[16]; int bk[16];
#pragma unroll
    for (int k = 0; k < 16; ++k) {
      long e = e0 + k * 256 + t;
      if (e < NE) {
        int d = dst[e], s = src[e];
        bk[k] = d >> 8;
        v[k] = ((unsigned)(d & 255) << 24) | (unsigned)s;
        atomicAdd(&hist[bk[k]], 1);
      } else bk[k] = -1;
    }
    __syncthreads();
    for (int b = t; b < NBUK; b += 256) {
      int c = hist[b];
      base[b] = c ? atomicAdd(&gcursor[b], c) : 0;
      hist[b] = 0;
    }
    __syncthreads();
#pragma unroll
    for (int k = 0; k < 16; ++k) {
      if (bk[k] >= 0) {
        int bkk = bk[k];
        int off = atomicAdd(&hist[bkk], 1);
        stage[(long)bkk * BCAP + base[bkk] + off] = v[k];
      }
    }
  }

  // ---- phase A2: gn0 sums over x (float4 = one node's 4 features) ----
  {
    const float4* x4 = (const float4*)x;
    float4 s4 = make_float4(0.f, 0.f, 0.f, 0.f);
    float4 q4 = make_float4(0.f, 0.f, 0.f, 0.f);
    int stride = gridDim.x * 256;
    for (int i = blockIdx.x * 256 + t; i < NN; i += stride) {
      float4 xv = x4[i];
      s4.x += xv.x; s4.y += xv.y; s4.z += xv.z; s4.w += xv.w;
      q4.x += xv.x * xv.x; q4.y += xv.y * xv.y; q4.z += xv.z * xv.z; q4.w += xv.w * xv.w;
    }
#pragma unroll
    for (int off = 32; off; off >>= 1) {
      s4.x += __shfl_xor(s4.x, off, 64); s4.y += __shfl_xor(s4.y, off, 64);
      s4.z += __shfl_xor(s4.z, off, 64); s4.w += __shfl_xor(s4.w, off, 64);
      q4.x += __shfl_xor(q4.x, off, 64); q4.y += __shfl_xor(q4.y, off, 64);
      q4.z += __shfl_xor(q4.z, off, 64); q4.w += __shfl_xor(q4.w, off, 64);
    }
    if (lane == 0) {
      atomicAdd(&sums0[0], s4.x); atomicAdd(&sums0[1], s4.y);
      atomicAdd(&sums0[2], s4.z); atomicAdd(&sums0[3], s4.w);
      atomicAdd(&sumsq0[0], q4.x); atomicAdd(&sumsq0[1], q4.y);
      atomicAdd(&sumsq0[2], q4.z); atomicAdd(&sumsq0[3], q4.w);
    }
  }

  gridbar(barc, barf, gridDim.x);

  // ---- phase B: scan bucket counts -> boff (block 0 only) ----
  if (blockIdx.x == 0) {
    int t2 = 2 * t;
    int c0 = (t2 < NBUK) ? gcursor[t2] : 0;
    int c1 = (t2 + 1 < NBUK) ? gcursor[t2 + 1] : 0;
    int ls = c0 + c1;
    int incl = ls;
#pragma unroll
    for (int off = 1; off < 64; off <<= 1) {
      int u = __shfl_up(incl, off, 64);
      if (lane >= off) incl += u;
    }
    if (lane == 63) ws[t >> 6] = incl;
    __syncthreads();
    int woff = 0;
    if (t >= 64) woff += ws[0];
    if (t >= 128) woff += ws[1];
    if (t >= 192) woff += ws[2];
    int excl = incl - ls + woff;
    if (t2 < NBUK) boff[t2] = excl;
    if (t2 + 1 < NBUK) boff[t2 + 1] = excl + c0;
    if (t == 0) { boff[NBUK] = NE; rowptr[NN] = NE; }
  }

  gridbar(barc, barf, gridDim.x);

  // ---- phase C: per-bucket counting sort -> col, rowptr, dinv (1 bucket per block) ----
  for (int b = blockIdx.x; b < NBUK; b += gridDim.x) {
    __syncthreads();
    long sb = (long)b * BCAP;
    int b0 = boff[b], cb = boff[b + 1] - b0;
    hist256[t] = 0;
    __syncthreads();
    for (int j = t; j < cb; j += 256)
      atomicAdd(&hist256[stage[sb + j] >> 24], 1);
    __syncthreads();
    int c = hist256[t];
    int incl = c;
#pragma unroll
    for (int off = 1; off < 64; off <<= 1) {
      int u = __shfl_up(incl, off, 64);
      if (lane >= off) incl += u;
    }
    if (lane == 63) ws[t >> 6] = incl;
    __syncthreads();
    int woff = 0;
    if (t >= 64) woff += ws[0];
    if (t >= 128) woff += ws[1];
    if (t >= 192) woff += ws[2];
    int gbase = b0 + (incl - c) + woff;
    int node = b * 256 + t;
    if (node < NN) {
      rowptr[node] = gbase;
      dinv[node] = rsqrtf((float)c + 1.0f);
    }
    cur256[t] = gbase;
    __syncthreads();
    for (int j = t; j < cb; j += 256) {
      unsigned v = stage[sb + j];
      int pos = atomicAdd(&cur256[v >> 24], 1);
      col[pos] = (int)(v & 0xffffffu);
    }
  }
}

// ---------------- fused GraphNorm-apply + matmul + dinv prescale -> bf16 y ----------------
template <int D>
__global__ __launch_bounds__(256) void k_mm(const float* __restrict__ hin, const float* __restrict__ W,
                                            const float* __restrict__ gw, const float* __restrict__ gb,
                                            const float* __restrict__ gms,
                                            const float* __restrict__ sums, const float* __restrict__ sumsq,
                                            const float* __restrict__ dinv,
                                            unsigned* __restrict__ y32) {
  __shared__ float4 Ws4[D][16];
  __shared__ float4 woff4[16];
  __shared__ float scale[D], shift[D];
  __shared__ float hl[16][68];      // stride 68: 16B-aligned rows, bank-shift 4
  int t = threadIdx.x;
  if (t < D) {
    float sc, sh;
    gn_affine(t, gw, gb, gms, sums, sumsq, sc, sh);
    scale[t] = sc; shift[t] = sh;
  }
  __syncthreads();
  for (int idx = t; idx < D * 64; idx += 256) {
    int k = idx >> 6;
    ((float*)Ws4)[idx] = scale[k] * W[idx];
  }
  __syncthreads();
  if (t < 64) {
    float o = 0.f;
#pragma unroll
    for (int k = 0; k < D; ++k) o += shift[k] * W[k * 64 + t];
    ((float*)woff4)[t] = o;
  }
  __syncthreads();

  int row = t >> 4, cg = t & 15;
  const int nG = NN / 16;  // 6250, exact
  for (int g = blockIdx.x; g < nG; g += gridDim.x) {
    if (D == 64) {
      *(float4*)&hl[row][cg * 4] = *(const float4*)(hin + (long)(g * 16 + row) * 64 + cg * 4);
    } else {
      if (t < 64) hl[t >> 2][t & 3] = hin[g * 64 + t];
    }
    __syncthreads();
    float4 acc = woff4[cg];
#pragma unroll
    for (int k = 0; k < D; ++k) {
      float hk = hl[row][k];
      float4 w4 = Ws4[k][cg];
      acc.x += hk * w4.x; acc.y += hk * w4.y;
      acc.z += hk * w4.z; acc.w += hk * w4.w;
    }
    int node = g * 16 + row;
    float di = dinv[node];
    uint2 u;
    u.x = packbf2(di * acc.x, di * acc.y);
    u.y = packbf2(di * acc.z, di * acc.w);
    *(uint2*)(y32 + (long)node * 32 + 2 * cg) = u;
    __syncthreads();
  }
}

// ---------------- fused CSR gather (bf16, octet layout, next-node rowptr prefetch) ----------------
#define ACC4(W) { f[0]+=bflo(W.x); f[1]+=bfhi(W.x); f[2]+=bflo(W.y); f[3]+=bfhi(W.y); \
                  f[4]+=bflo(W.z); f[5]+=bfhi(W.z); f[6]+=bflo(W.w); f[7]+=bfhi(W.w); }

// PR: apply prelu; HB: write bf16 h copy (no fp32 h write)
template <bool PR, bool HB>
__global__ __launch_bounds__(256) void k_gather_fin(const uint4* __restrict__ y4,
                                                    const int* __restrict__ rowptr, const int* __restrict__ col,
                                                    const float* __restrict__ dinv,
                                                    const float* __restrict__ b, const float* __restrict__ a,
                                                    float* __restrict__ h, uint4* __restrict__ hb4,
                                                    float* __restrict__ sums, float* __restrict__ sumsq) {
  __shared__ float lsum[4][64], lsq[4][64];
  int t = threadIdx.x, lane = t & 63, w = t >> 6;
  int o = lane >> 3, l7 = lane & 7;
  float bv[8], av[8];
#pragma unroll
  for (int k = 0; k < 8; ++k) {
    bv[k] = b[8 * l7 + k];
    av[k] = PR ? a[8 * l7 + k] : 1.f;
  }
  float sa[8] = {0,0,0,0,0,0,0,0}, qa[8] = {0,0,0,0,0,0,0,0};
  int nwaves = gridDim.x * 4;
  int i = blockIdx.x * 4 + w;
  int p = 0, p1 = 0;
  if (i < NN) { p = rowptr[i]; p1 = rowptr[i + 1]; }
  while (i < NN) {
    int inext = i + nwaves;
    int pn = 0, pn1 = 0;
    if (inext < NN) { pn = rowptr[inext]; pn1 = rowptr[inext + 1]; }  // prefetch next node
    float f[8] = {0,0,0,0,0,0,0,0};
    for (; p + 16 <= p1; p += 16) {
      int c0 = col[p + o], c1 = col[p + 8 + o];
      uint4 wa = y4[c0 * 8 + l7];
      uint4 wb = y4[c1 * 8 + l7];
      ACC4(wa); ACC4(wb);
    }
    if (p + 8 <= p1) {
      int c0 = col[p + o];
      uint4 wa = y4[c0 * 8 + l7];
      ACC4(wa);
      p += 8;
    }
    {
      int r = p1 - p;                     // 0..7
      int c = (o < r) ? col[p + o] : ((o == r) ? i : -1);
      if (c >= 0) {
        uint4 wa = y4[c * 8 + l7];
        ACC4(wa);
      }
    }
#pragma unroll
    for (int k = 0; k < 8; ++k) {
      float v = f[k];
      v += __shfl_xor(v, 8, 64);
      v += __shfl_xor(v, 16, 64);
      v += __shfl_xor(v, 32, 64);
      f[k] = v;
    }
    float di = dinv[i];
    float vo[8];
#pragma unroll
    for (int k = 0; k < 8; ++k) {
      float v = di * f[k] + bv[k];
      if (PR && v < 0.f) v *= av[k];
      vo[k] = v;
      sa[k] += v; qa[k] += v * v;
    }
    if (o == 0) {
      if (HB) {
        uint4 u;
        u.x = packbf2(vo[0], vo[1]); u.y = packbf2(vo[2], vo[3]);
        u.z = packbf2(vo[4], vo[5]); u.w = packbf2(vo[6], vo[7]);
        hb4[(long)i * 8 + l7] = u;
      } else {
        *(float4*)(h + (long)i * 64 + 8 * l7)     = make_float4(vo[0], vo[1], vo[2], vo[3]);
        *(float4*)(h + (long)i * 64 + 8 * l7 + 4) = make_float4(vo[4], vo[5], vo[6], vo[7]);
      }
    }
    i = inext; p = pn; p1 = pn1;
  }
  if (o == 0) {
#pragma unroll
    for (int k = 0; k < 8; ++k) { lsum[w][8 * l7 + k] = sa[k]; lsq[w][8 * l7 + k] = qa[k]; }
  }
  __syncthreads();
  if (t < 64) {
    float S = lsum[0][t] + lsum[1][t] + lsum[2][t] + lsum[3][t];
    float Q = lsq[0][t] + lsq[1][t] + lsq[2][t] + lsq[3][t];
    atomicAdd(&sums[t], S);
    atomicAdd(&sumsq[t], Q);
  }
}

// ---------------- Set2Set persistent tail ----------------
struct TailSmem {
  float gm[32], gz[32], gr[32][64];
  float hsL[64], cL[64], qsL[128], gL[256], red[256], sf[NB_ATT], rr4[4][64];
};

static __device__ void att_phase(TailSmem& S, const uint4* __restrict__ hb4,
                                 const float* __restrict__ sm, float* __restrict__ part) {
  int t = threadIdx.x;
  int grp = t >> 3, l7 = t & 7;
  float hvr[8];
#pragma unroll
  for (int k = 0; k < 8; ++k) hvr[k] = sm[SM_HV + 8 * l7 + k];
  float eoff = sm[SM_EOFF];
  float m = -3.4e38f, z = 0.f;
  float r[8] = {0,0,0,0,0,0,0,0};
  int ngrp = gridDim.x * 32;
  for (int i = blockIdx.x * 32 + grp; i < NN; i += ngrp) {
    uint4 hw = hb4[(long)i * 8 + l7];
    float hx[8] = { bflo(hw.x), bfhi(hw.x), bflo(hw.y), bfhi(hw.y),
                    bflo(hw.z), bfhi(hw.z), bflo(hw.w), bfhi(hw.w) };
    float dot = 0.f;
#pragma unroll
    for (int k = 0; k < 8; ++k) dot += hx[k] * hvr[k];
    dot += __shfl_xor(dot, 1, 64);
    dot += __shfl_xor(dot, 2, 64);
    dot += __shfl_xor(dot, 4, 64);
    float e = dot + eoff;
    float mn = fmaxf(m, e);
    float sc = expf(m - mn);
    float pb = expf(e - mn);
    z = z * sc + pb;
#pragma unroll
    for (int k = 0; k < 8; ++k) r[k] = r[k] * sc + pb * hx[k];
    m = mn;
  }
#pragma unroll
  for (int k = 0; k < 8; ++k) S.gr[grp][8 * l7 + k] = r[k];
  if (l7 == 0) { S.gm[grp] = m; S.gz[grp] = z; }
  __syncthreads();
  if (t < 64) {
    float mb = S.gm[0];
#pragma unroll
    for (int k = 1; k < 32; ++k) mb = fmaxf(mb, S.gm[k]);
    float rb = 0.f, zb = 0.f;
#pragma unroll 8
    for (int k = 0; k < 32; ++k) {
      float scl = expf(S.gm[k] - mb);
      rb += S.gr[k][t] * scl;
      zb += S.gz[k] * scl;
    }
    part[blockIdx.x * 68 + t] = rb;
    if (t == 0) { part[blockIdx.x * 68 + 64] = mb; part[blockIdx.x * 68 + 65] = zb; }
  }
  __syncthreads();
}

// mode 0: boot (no reduce; LSTM from q*=0), 1: mid step, 2: final (write out, no LSTM)
static __device__ void fin_phase(TailSmem& S, const float* __restrict__ part,
                                 const float* __restrict__ gw, const float* __restrict__ gb,
                                 const float* __restrict__ gms,
                                 const float* __restrict__ sums, const float* __restrict__ sumsq,
                                 const float* __restrict__ Wih, const float* __restrict__ Whh,
                                 const float* __restrict__ bih, const float* __restrict__ bhh,
                                 float* __restrict__ sm, float* __restrict__ out, int mode) {
  int t = threadIdx.x, lane = t & 63, w = t >> 6;
  if (t < 64) { S.hsL[t] = sm[SM_HS + t]; S.cL[t] = sm[SM_C + t]; }
  __syncthreads();
  if (mode > 0) {
    float mv = part[t * 68 + 64];
    S.red[t] = mv; __syncthreads();
    for (int s = 128; s; s >>= 1) { if (t < s) S.red[t] = fmaxf(S.red[t], S.red[t + s]); __syncthreads(); }
    float mg = S.red[0];
    __syncthreads();
    float sc_ = expf(mv - mg);
    S.sf[t] = sc_;
    S.red[t] = part[t * 68 + 65] * sc_; __syncthreads();
    for (int s = 128; s; s >>= 1) { if (t < s) S.red[t] += S.red[t + s]; __syncthreads(); }
    float zg = S.red[0];
    __syncthreads();
    float racc = 0.f;
#pragma unroll 8
    for (int j = 0; j < 64; ++j) {
      int bk = 4 * j + w;
      racc += part[bk * 68 + lane] * S.sf[bk];
    }
    S.rr4[w][lane] = racc;
    __syncthreads();
    if (t < 64) {
      float rg = S.rr4[0][t] + S.rr4[1][t] + S.rr4[2][t] + S.rr4[3][t];
      float sc, sh;
      gn_affine(t, gw, gb, gms, sums, sumsq, sc, sh);
      float rr = sc * (rg / zg) + sh;
      S.qsL[t] = S.hsL[t]; S.qsL[64 + t] = rr;
      if (mode == 2) { out[t] = S.hsL[t]; out[64 + t] = rr; }
    }
  } else {
    if (t < 64) { S.qsL[t] = 0.f; S.qsL[64 + t] = 0.f; S.hsL[t] = 0.f; S.cL[t] = 0.f; }
  }
  __syncthreads();
  if (mode == 2) return;
  float g = bih[t] + bhh[t];
#pragma unroll 16
  for (int k = 0; k < 128; ++k) g += S.qsL[k] * Wih[t * 128 + k];
#pragma unroll 16
  for (int k = 0; k < 64; ++k) g += S.hsL[k] * Whh[t * 64 + k];
  S.gL[t] = g;
  __syncthreads();
  if (t < 64) {
    float ig = 1.f / (1.f + expf(-S.gL[t]));
    float fg = 1.f / (1.f + expf(-S.gL[64 + t]));
    float gg = tanhf(S.gL[128 + t]);
    float og = 1.f / (1.f + expf(-S.gL[192 + t]));
    float c = fg * S.cL[t] + ig * gg;
    float hsn = og * tanhf(c);
    sm[SM_C + t] = c;
    sm[SM_HS + t] = hsn;
    float sc, sh;
    gn_affine(t, gw, gb, gms, sums, sumsq, sc, sh);
    sm[SM_HV + t] = sc * hsn;
    S.red[t] = sh * hsn;
  }
  __syncthreads();
  if (t == 0) {
    float s = 0.f;
    for (int k = 0; k < 64; ++k) s += S.red[k];
    sm[SM_EOFF] = s;
  }
  __syncthreads();
}

__global__ __launch_bounds__(256) void k_tail(const uint4* __restrict__ hb4, float* __restrict__ part,
                                              const float* __restrict__ gw, const float* __restrict__ gb,
                                              const float* __restrict__ gms,
                                              const float* __restrict__ sums, const float* __restrict__ sumsq,
                                              const float* __restrict__ Wih, const float* __restrict__ Whh,
                                              const float* __restrict__ bih, const float* __restrict__ bhh,
                                              float* __restrict__ sm, float* __restrict__ out,
                                              int* __restrict__ barc, unsigned* __restrict__ barf) {
  __shared__ TailSmem S;
  if (blockIdx.x == 0)
    fin_phase(S, part, gw, gb, gms, sums, sumsq, Wih, Whh, bih, bhh, sm, nullptr, 0);
  for (int s = 0; s < 3; ++s) {
    gridbar(barc, barf, gridDim.x);
    att_phase(S, hb4, sm, part);
    gridbar(barc, barf, gridDim.x);
    if (blockIdx.x == 0)
      fin_phase(S, part, gw, gb, gms, sums, sumsq, Wih, Whh, bih, bhh, sm,
                (s == 2) ? out : nullptr, (s == 2) ? 2 : 1);
  }
}

extern "C" void kernel_launch(void* const* d_in, const int* in_sizes, int n_in,
                              void* d_out, int out_size, void* d_ws, size_t ws_size,
                              hipStream_t stream) {
  const float* x     = (const float*)d_in[0];
  const float* gn0_w = (const float*)d_in[1];
  const float* gn0_b = (const float*)d_in[2];
  const float* gn0_ms= (const float*)d_in[3];
  const float* W1    = (const float*)d_in[4];
  const float* b1    = (const float*)d_in[5];
  const float* a1    = (const float*)d_in[6];
  const float* gn1_w = (const float*)d_in[7];
  const float* gn1_b = (const float*)d_in[8];
  const float* gn1_ms= (const float*)d_in[9];
  const float* W2    = (const float*)d_in[10];
  const float* b2    = (const float*)d_in[11];
  const float* a2    = (const float*)d_in[12];
  const float* gn2_w = (const float*)d_in[13];
  const float* gn2_b = (const float*)d_in[14];
  const float* gn2_ms= (const float*)d_in[15];
  const float* W3    = (const float*)d_in[16];
  const float* b3    = (const float*)d_in[17];
  const float* gn3_w = (const float*)d_in[18];
  const float* gn3_b = (const float*)d_in[19];
  const float* gn3_ms= (const float*)d_in[20];
  const float* Wih   = (const float*)d_in[21];
  const float* Whh   = (const float*)d_in[22];
  const float* bih   = (const float*)d_in[23];
  const float* bhh   = (const float*)d_in[24];
  const int*   eidx  = (const int*)d_in[25];
  const int* esrc = eidx;
  const int* edst = eidx + NE;

  float* sm   = (float*)d_ws;
  int* gcursor= (int*)(sm + SM_GCUR);          // 392 ints, zeroed by memset
  int* barc   = (int*)(sm + SM_BAR);
  unsigned* barf = (unsigned*)(sm + SM_BAR + 1);
  int* barc2  = (int*)(sm + SM_BAR + 2);
  unsigned* barf2 = (unsigned*)(sm + SM_BAR + 3);
  float* dinv = sm + OFF_DINV;
  float* h    = sm + OFF_H;
  unsigned* stage = (unsigned*)(sm + OFF_H);   // aliases h; dead before first gather
  uint4* hb4  = (uint4*)(sm + OFF_H);          // aliases h; written only after h is dead
  unsigned* y32 = (unsigned*)(sm + OFF_Y32);
  const uint4* y4 = (const uint4*)y32;
  float* part = sm + OFF_PART;
  int* col    = (int*)(sm + OFF_INT);          // NE
  int* rowptr = col + NE;                      // NPAD (NN+1)
  int* boff   = rowptr + NPAD;                 // NBUK+1
  float* out  = (float*)d_out;

  hipMemsetAsync(sm, 0, SM_ZEND * sizeof(float), stream);

  // fused CSR build + gn0 stats (one persistent kernel)
  k_build<<<NB_BUILD, 256, 0, stream>>>(esrc, edst, x, gcursor, stage, boff, col, rowptr, dinv,
                                        sm + SM_SUMS(0), sm + SM_SUMSQ(0), barc, barf);

  // layer 1
  k_mm<4><<<1024, 256, 0, stream>>>(x, W1, gn0_w, gn0_b, gn0_ms,
                                    sm + SM_SUMS(0), sm + SM_SUMSQ(0), dinv, y32);
  k_gather_fin<true, false><<<2048, 256, 0, stream>>>(y4, rowptr, col, dinv, b1, a1, h, nullptr,
                                                      sm + SM_SUMS(1), sm + SM_SUMSQ(1));
  // layer 2
  k_mm<64><<<1024, 256, 0, stream>>>(h, W2, gn1_w, gn1_b, gn1_ms,
                                     sm + SM_SUMS(1), sm + SM_SUMSQ(1), dinv, y32);
  k_gather_fin<true, false><<<2048, 256, 0, stream>>>(y4, rowptr, col, dinv, b2, a2, h, nullptr,
                                                      sm + SM_SUMS(2), sm + SM_SUMSQ(2));
  // layer 3 (no prelu): writes bf16 h copy only
  k_mm<64><<<1024, 256, 0, stream>>>(h, W3, gn2_w, gn2_b, gn2_ms,
                                     sm + SM_SUMS(2), sm + SM_SUMSQ(2), dinv, y32);
  k_gather_fin<false, true><<<2048, 256, 0, stream>>>(y4, rowptr, col, dinv, b3, nullptr, nullptr, hb4,
                                                      sm + SM_SUMS(3), sm + SM_SUMSQ(3));

  // Set2Set persistent tail: boot + 3x(att + fin)
  k_tail<<<NB_ATT, 256, 0, stream>>>(hb4, part, gn3_w, gn3_b, gn3_ms,
                                     sm + SM_SUMS(3), sm + SM_SUMSQ(3),
                                     Wih, Whh, bih, bhh, sm, out, barc2, barf2);
}

// Round 9
// 846.664 us; speedup vs baseline: 1.0305x; 1.0305x over previous
//
#include <hip/hip_runtime.h>

#define NN 100000
#define NE 1600000
#define HID 64
#define EPSV 1e-5f
#define NB_ATT 256
#define NGRP 12500               // NN/8 node-groups for slice gather

// bucketed CSR build
#define NBUK 391                 // ceil(NN/256), bucket = dst>>8
#define BCAP 4608                // slots per bucket (lambda~4092, +8 sigma)
#define BTILE 4096               // edges per bin tile
#define NTILES 391               // ceil(NE/BTILE)

// ---------- small scratch layout (float indices into ws) ----------
#define SM_SUMS(l)  ((l)*128)
#define SM_SUMSQ(l) ((l)*128 + 64)
#define SM_HS       512
#define SM_C        576
#define SM_HV       768          // 64 floats
#define SM_EOFF     832
#define SM_GCUR     1024         // 392 ints (zeroed by memset)
#define SM_ZEND     1424         // memset covers [0, SM_ZEND)

// big buffers (float offsets)
#define NPAD        100352L
#define OFF_DINV    1424L
#define OFF_H       (OFF_DINV + NPAD)       // 6.4M floats; stage AND hb alias this region
#define OFF_Y32     (OFF_H + 6400000L)      // 3.2M uints (bf16x2)
#define OFF_PART    (OFF_Y32 + 3200000L)    // NB_ATT*68
#define OFF_INT     (OFF_PART + 69632L)

static __device__ __forceinline__ unsigned bf16rne(float f) {
  unsigned u = __float_as_uint(f);
  return (u + 0x7fffu + ((u >> 16) & 1u)) >> 16;
}
static __device__ __forceinline__ unsigned packbf2(float lo, float hi) {
  return bf16rne(lo) | (bf16rne(hi) << 16);
}
static __device__ __forceinline__ float bflo(unsigned w) { return __uint_as_float(w << 16); }
static __device__ __forceinline__ float bfhi(unsigned w) { return __uint_as_float(w & 0xffff0000u); }

// GraphNorm affine from accumulated sums: gn(x) = sc*x + sh  (per feature j)
static __device__ __forceinline__ void gn_affine(int j, const float* w, const float* b,
                                                 const float* ms, const float* sums,
                                                 const float* sumsq, float& sc, float& sh) {
  const float invn = 1.0f / (float)NN;
  float mean = sums[j] * invn;
  float ex2  = sumsq[j] * invn;
  float m    = ms[j];
  float var  = ex2 - m * mean * mean * (2.0f - m);
  sc = w[j] * rsqrtf(var + EPSV);
  sh = b[j] - sc * m * mean;
}

// ---------------- pass 1: bin edges into per-bucket staging + gn0 stats ----------------
// gcursor holds plain per-bucket COUNTS (zeroed by memset); base b*BCAP folded into addressing.
__global__ __launch_bounds__(256) void k_bin(const int* __restrict__ src, const int* __restrict__ dst,
                                             const float* __restrict__ x,
                                             int* __restrict__ gcursor, unsigned* __restrict__ stage,
                                             float* __restrict__ sums0, float* __restrict__ sumsq0) {
  __shared__ int hist[NBUK], base[NBUK];
  int t = threadIdx.x, lane = t & 63;
  long tile0 = (long)blockIdx.x * BTILE;
  for (int b = t; b < NBUK; b += 256) hist[b] = 0;
  __syncthreads();
  unsigned v[16]; int bk[16];
#pragma unroll
  for (int k = 0; k < 16; ++k) {
    long e = tile0 + k * 256 + t;
    if (e < NE) {
      int d = dst[e], s = src[e];
      bk[k] = d >> 8;
      v[k] = ((unsigned)(d & 255) << 24) | (unsigned)s;
      atomicAdd(&hist[bk[k]], 1);
    } else bk[k] = -1;
  }
  __syncthreads();
  for (int b = t; b < NBUK; b += 256) {
    int c = hist[b];
    base[b] = c ? atomicAdd(&gcursor[b], c) : 0;
    hist[b] = 0;
  }
  __syncthreads();
#pragma unroll
  for (int k = 0; k < 16; ++k) {
    if (bk[k] >= 0) {
      int bkk = bk[k];
      int off = atomicAdd(&hist[bkk], 1);
      stage[(long)bkk * BCAP + base[bkk] + off] = v[k];
    }
  }
  // gn0 stats over x (no barrier needed; completes before k_mm<4> by stream order)
  const float4* x4 = (const float4*)x;
  float4 s4 = make_float4(0.f, 0.f, 0.f, 0.f);
  float4 q4 = make_float4(0.f, 0.f, 0.f, 0.f);
  int stride = gridDim.x * 256;
  for (int i = blockIdx.x * 256 + t; i < NN; i += stride) {
    float4 xv = x4[i];
    s4.x += xv.x; s4.y += xv.y; s4.z += xv.z; s4.w += xv.w;
    q4.x += xv.x * xv.x; q4.y += xv.y * xv.y; q4.z += xv.z * xv.z; q4.w += xv.w * xv.w;
  }
#pragma unroll
  for (int off = 32; off; off >>= 1) {
    s4.x += __shfl_xor(s4.x, off, 64); s4.y += __shfl_xor(s4.y, off, 64);
    s4.z += __shfl_xor(s4.z, off, 64); s4.w += __shfl_xor(s4.w, off, 64);
    q4.x += __shfl_xor(q4.x, off, 64); q4.y += __shfl_xor(q4.y, off, 64);
    q4.z += __shfl_xor(q4.z, off, 64); q4.w += __shfl_xor(q4.w, off, 64);
  }
  if (lane == 0) {
    atomicAdd(&sums0[0], s4.x); atomicAdd(&sums0[1], s4.y);
    atomicAdd(&sums0[2], s4.z); atomicAdd(&sums0[3], s4.w);
    atomicAdd(&sumsq0[0], q4.x); atomicAdd(&sumsq0[1], q4.y);
    atomicAdd(&sumsq0[2], q4.z); atomicAdd(&sumsq0[3], q4.w);
  }
}

// ---------------- pass 1b: scan bucket counts -> boff ----------------
__global__ __launch_bounds__(512) void k_bscan(const int* __restrict__ gcursor,
                                               int* __restrict__ boff, int* __restrict__ rowptr) {
  __shared__ int ws[8];
  int t = threadIdx.x, lane = t & 63;
  int c = (t < NBUK) ? gcursor[t] : 0;
  int incl = c;
#pragma unroll
  for (int off = 1; off < 64; off <<= 1) {
    int u = __shfl_up(incl, off, 64);
    if (lane >= off) incl += u;
  }
  if (lane == 63) ws[t >> 6] = incl;
  __syncthreads();
  if (t == 0) {
    int s = 0;
#pragma unroll
    for (int w = 0; w < 8; ++w) { int tv = ws[w]; ws[w] = s; s += tv; }
  }
  __syncthreads();
  if (t < NBUK) boff[t] = incl - c + ws[t >> 6];
  if (t == 0) { boff[NBUK] = NE; rowptr[NN] = NE; }
}

// ---------------- pass 2: per-bucket counting sort -> col, rowptr, dinv ----------------
__global__ __launch_bounds__(256) void k_bsort(const unsigned* __restrict__ stage,
                                               const int* __restrict__ boff,
                                               int* __restrict__ col, int* __restrict__ rowptr,
                                               float* __restrict__ dinv) {
  __shared__ int hist[256], cur[256];
  __shared__ int ws[4];
  int b = blockIdx.x;
  int t = threadIdx.x, lane = t & 63;
  long sb = (long)b * BCAP;
  int b0 = boff[b], cb = boff[b + 1] - b0;
  hist[t] = 0;
  __syncthreads();
  for (int j = t; j < cb; j += 256)
    atomicAdd(&hist[stage[sb + j] >> 24], 1);
  __syncthreads();
  int c = hist[t];
  int incl = c;
#pragma unroll
  for (int off = 1; off < 64; off <<= 1) {
    int u = __shfl_up(incl, off, 64);
    if (lane >= off) incl += u;
  }
  if (lane == 63) ws[t >> 6] = incl;
  __syncthreads();
  int woff = 0;
  if (t >= 64) woff += ws[0];
  if (t >= 128) woff += ws[1];
  if (t >= 192) woff += ws[2];
  int gbase = b0 + (incl - c) + woff;
  int node = b * 256 + t;
  if (node < NN) {
    rowptr[node] = gbase;
    dinv[node] = rsqrtf((float)c + 1.0f);
  }
  cur[t] = gbase;
  __syncthreads();
  for (int j = t; j < cb; j += 256) {
    unsigned v = stage[sb + j];
    int pos = atomicAdd(&cur[v >> 24], 1);
    col[pos] = (int)(v & 0xffffffu);
  }
}

// ---------------- fused GraphNorm-apply + matmul + dinv prescale -> bf16 y ----------------
template <int D>
__global__ __launch_bounds__(256) void k_mm(const float* __restrict__ hin, const float* __restrict__ W,
                                            const float* __restrict__ gw, const float* __restrict__ gb,
                                            const float* __restrict__ gms,
                                            const float* __restrict__ sums, const float* __restrict__ sumsq,
                                            const float* __restrict__ dinv,
                                            unsigned* __restrict__ y32) {
  __shared__ float4 Ws4[D][16];
  __shared__ float4 woff4[16];
  __shared__ float scale[D], shift[D];
  __shared__ float hl[16][68];      // stride 68: 16B-aligned rows, bank-shift 4
  int t = threadIdx.x;
  if (t < D) {
    float sc, sh;
    gn_affine(t, gw, gb, gms, sums, sumsq, sc, sh);
    scale[t] = sc; shift[t] = sh;
  }
  __syncthreads();
  for (int idx = t; idx < D * 64; idx += 256) {
    int k = idx >> 6;
    ((float*)Ws4)[idx] = scale[k] * W[idx];
  }
  __syncthreads();
  if (t < 64) {
    float o = 0.f;
#pragma unroll
    for (int k = 0; k < D; ++k) o += shift[k] * W[k * 64 + t];
    ((float*)woff4)[t] = o;
  }
  __syncthreads();

  int row = t >> 4, cg = t & 15;
  const int nG = NN / 16;  // 6250, exact
  for (int g = blockIdx.x; g < nG; g += gridDim.x) {
    if (D == 64) {
      *(float4*)&hl[row][cg * 4] = *(const float4*)(hin + (long)(g * 16 + row) * 64 + cg * 4);
    } else {
      if (t < 64) hl[t >> 2][t & 3] = hin[g * 64 + t];
    }
    __syncthreads();
    float4 acc = woff4[cg];
#pragma unroll
    for (int k = 0; k < D; ++k) {
      float hk = hl[row][k];
      float4 w4 = Ws4[k][cg];
      acc.x += hk * w4.x; acc.y += hk * w4.y;
      acc.z += hk * w4.z; acc.w += hk * w4.w;
    }
    int node = g * 16 + row;
    float di = dinv[node];
    uint2 u;
    u.x = packbf2(di * acc.x, di * acc.y);
    u.y = packbf2(di * acc.z, di * acc.w);
    *(uint2*)(y32 + (long)node * 32 + 2 * cg) = u;
    __syncthreads();
  }
}

// ---------------- XCD-sliced CSR gather ----------------
// Block handles feature slice s = blockIdx&7 (16B of each y row). Under round-robin
// blockIdx->XCD mapping all slice-s blocks share one XCD whose y working set is 1.6MB
// (L2-resident) instead of 12.8MB. Wave: 8 nodes (lane = node n * edge-sub j).
#define ACCW(WV) { f[0]+=bflo(WV.x); f[1]+=bfhi(WV.x); f[2]+=bflo(WV.y); f[3]+=bfhi(WV.y); \
                   f[4]+=bflo(WV.z); f[5]+=bfhi(WV.z); f[6]+=bflo(WV.w); f[7]+=bfhi(WV.w); }

template <bool PR, bool HB>
__global__ __launch_bounds__(256) void k_gather_fin(const uint4* __restrict__ y4x,
                                                    const int* __restrict__ rowptr, const int* __restrict__ col,
                                                    const float* __restrict__ dinv,
                                                    const float* __restrict__ b, const float* __restrict__ a,
                                                    float* __restrict__ h, uint4* __restrict__ hb4,
                                                    float* __restrict__ sums, float* __restrict__ sumsq) {
  __shared__ float ssum[8], ssq[8];
  int t = threadIdx.x, lane = t & 63, w = t >> 6;
  int n = lane >> 3, j = lane & 7;
  int s = blockIdx.x & 7;
  if (t < 8) { ssum[t] = 0.f; ssq[t] = 0.f; }
  __syncthreads();
  float bv[8], av[8];
#pragma unroll
  for (int k = 0; k < 8; ++k) {
    bv[k] = b[8 * s + k];
    av[k] = PR ? a[8 * s + k] : 1.f;
  }
  float sa[8] = {0,0,0,0,0,0,0,0}, qa[8] = {0,0,0,0,0,0,0,0};
  int gstride = (gridDim.x >> 3) * 4;
  for (int g = (blockIdx.x >> 3) * 4 + w; g < NGRP; g += gstride) {
    int i0 = g * 8;
    int r = (lane < 9) ? rowptr[i0 + lane] : 0;
    int p0 = __shfl(r, n, 64);
    int p1 = __shfl(r, n + 1, 64);
    float f[8] = {0,0,0,0,0,0,0,0};
    for (int p = p0 + j; p < p1; p += 8) {
      int c = col[p];
      uint4 wv = y4x[(long)c * 8 + s];
      ACCW(wv);
    }
    if (((p1 - p0) & 7) == j) {           // self-loop: exactly one lane per node
      uint4 wv = y4x[(long)(i0 + n) * 8 + s];
      ACCW(wv);
    }
#pragma unroll
    for (int k = 0; k < 8; ++k) {
      float v = f[k];
      v += __shfl_xor(v, 1, 64);
      v += __shfl_xor(v, 2, 64);
      v += __shfl_xor(v, 4, 64);
      f[k] = v;
    }
    if (j == 0) {
      int i = i0 + n;
      float di = dinv[i];
      float vo[8];
#pragma unroll
      for (int k = 0; k < 8; ++k) {
        float v = di * f[k] + bv[k];
        if (PR && v < 0.f) v *= av[k];
        vo[k] = v;
        sa[k] += v; qa[k] += v * v;
      }
      if (HB) {
        uint4 u;
        u.x = packbf2(vo[0], vo[1]); u.y = packbf2(vo[2], vo[3]);
        u.z = packbf2(vo[4], vo[5]); u.w = packbf2(vo[6], vo[7]);
        hb4[(long)i * 8 + s] = u;
      } else {
        *(float4*)(h + (long)i * 64 + 8 * s)     = make_float4(vo[0], vo[1], vo[2], vo[3]);
        *(float4*)(h + (long)i * 64 + 8 * s + 4) = make_float4(vo[4], vo[5], vo[6], vo[7]);
      }
    }
  }
  if (j == 0) {
#pragma unroll
    for (int k = 0; k < 8; ++k) { atomicAdd(&ssum[k], sa[k]); atomicAdd(&ssq[k], qa[k]); }
  }
  __syncthreads();
  if (t < 8) {
    atomicAdd(&sums[8 * s + t], ssum[t]);
    atomicAdd(&sumsq[8 * s + t], ssq[t]);
  }
}

// ---------------- Set2Set: fused attention pass (bf16 h, 8-lane groups) ----------------
__global__ __launch_bounds__(256) void k_att(const uint4* __restrict__ hb4, const float* __restrict__ sm,
                                             float* __restrict__ part) {
  __shared__ float gm[32], gz[32], gr[32][64];
  int t = threadIdx.x;
  int grp = t >> 3, l7 = t & 7;
  float hvr[8];
#pragma unroll
  for (int k = 0; k < 8; ++k) hvr[k] = sm[SM_HV + 8 * l7 + k];
  float eoff = sm[SM_EOFF];
  float m = -3.4e38f, z = 0.f;
  float r[8] = {0,0,0,0,0,0,0,0};
  int ngrp = gridDim.x * 32;
  for (int i = blockIdx.x * 32 + grp; i < NN; i += ngrp) {
    uint4 hw = hb4[(long)i * 8 + l7];
    float hx[8] = { bflo(hw.x), bfhi(hw.x), bflo(hw.y), bfhi(hw.y),
                    bflo(hw.z), bfhi(hw.z), bflo(hw.w), bfhi(hw.w) };
    float dot = 0.f;
#pragma unroll
    for (int k = 0; k < 8; ++k) dot += hx[k] * hvr[k];
    dot += __shfl_xor(dot, 1, 64);
    dot += __shfl_xor(dot, 2, 64);
    dot += __shfl_xor(dot, 4, 64);
    float e = dot + eoff;
    float mn = fmaxf(m, e);
    float sc = expf(m - mn);
    float pb = expf(e - mn);
    z = z * sc + pb;
#pragma unroll
    for (int k = 0; k < 8; ++k) r[k] = r[k] * sc + pb * hx[k];
    m = mn;
  }
#pragma unroll
  for (int k = 0; k < 8; ++k) gr[grp][8 * l7 + k] = r[k];
  if (l7 == 0) { gm[grp] = m; gz[grp] = z; }
  __syncthreads();
  if (t < 64) {
    float mb = gm[0];
#pragma unroll
    for (int k = 1; k < 32; ++k) mb = fmaxf(mb, gm[k]);
    float rb = 0.f, zb = 0.f;
#pragma unroll 8
    for (int k = 0; k < 32; ++k) {
      float scl = expf(gm[k] - mb);
      rb += gr[k][t] * scl;
      zb += gz[k] * scl;
    }
    part[blockIdx.x * 68 + t] = rb;
    if (t == 0) { part[blockIdx.x * 68 + 64] = mb; part[blockIdx.x * 68 + 65] = zb; }
  }
}

// ---------------- Set2Set finish: reduce partials -> q_star -> LSTM(next) -> hv ----------------
// mode 0: boot (no reduce; LSTM from q*=0), 1: mid step, 2: final (write out, no LSTM)
__global__ __launch_bounds__(256) void k_attfin(const float* __restrict__ part,
                                                const float* __restrict__ gw, const float* __restrict__ gb,
                                                const float* __restrict__ gms,
                                                const float* __restrict__ sums, const float* __restrict__ sumsq,
                                                const float* __restrict__ Wih, const float* __restrict__ Whh,
                                                const float* __restrict__ bih, const float* __restrict__ bhh,
                                                float* __restrict__ sm, float* __restrict__ out, int mode) {
  __shared__ float hsL[64], cL[64], qsL[128], gL[256], red[256], sf[NB_ATT], rr4[4][64];
  int t = threadIdx.x, lane = t & 63, w = t >> 6;
  if (t < 64) { hsL[t] = sm[SM_HS + t]; cL[t] = sm[SM_C + t]; }
  __syncthreads();
  if (mode > 0) {
    float mv = part[t * 68 + 64];
    red[t] = mv; __syncthreads();
    for (int s = 128; s; s >>= 1) { if (t < s) red[t] = fmaxf(red[t], red[t + s]); __syncthreads(); }
    float mg = red[0];
    __syncthreads();
    float sc_ = expf(mv - mg);
    sf[t] = sc_;
    red[t] = part[t * 68 + 65] * sc_; __syncthreads();
    for (int s = 128; s; s >>= 1) { if (t < s) red[t] += red[t + s]; __syncthreads(); }
    float zg = red[0];
    __syncthreads();
    float racc = 0.f;
#pragma unroll 8
    for (int jx = 0; jx < 64; ++jx) {
      int bk = 4 * jx + w;
      racc += part[bk * 68 + lane] * sf[bk];
    }
    rr4[w][lane] = racc;
    __syncthreads();
    if (t < 64) {
      float rg = rr4[0][t] + rr4[1][t] + rr4[2][t] + rr4[3][t];
      float sc, sh;
      gn_affine(t, gw, gb, gms, sums, sumsq, sc, sh);
      float rr = sc * (rg / zg) + sh;
      qsL[t] = hsL[t]; qsL[64 + t] = rr;
      if (mode == 2) { out[t] = hsL[t]; out[64 + t] = rr; }
    }
  } else {
    if (t < 64) { qsL[t] = 0.f; qsL[64 + t] = 0.f; hsL[t] = 0.f; cL[t] = 0.f; }
  }
  __syncthreads();
  if (mode == 2) return;
  float g = bih[t] + bhh[t];
#pragma unroll 16
  for (int k = 0; k < 128; ++k) g += qsL[k] * Wih[t * 128 + k];
#pragma unroll 16
  for (int k = 0; k < 64; ++k) g += hsL[k] * Whh[t * 64 + k];
  gL[t] = g;
  __syncthreads();
  if (t < 64) {
    float ig = 1.f / (1.f + expf(-gL[t]));
    float fg = 1.f / (1.f + expf(-gL[64 + t]));
    float gg = tanhf(gL[128 + t]);
    float og = 1.f / (1.f + expf(-gL[192 + t]));
    float c = fg * cL[t] + ig * gg;
    float hsn = og * tanhf(c);
    sm[SM_C + t] = c;
    sm[SM_HS + t] = hsn;
    float sc, sh;
    gn_affine(t, gw, gb, gms, sums, sumsq, sc, sh);
    sm[SM_HV + t] = sc * hsn;
    red[t] = sh * hsn;
  }
  __syncthreads();
  if (t == 0) {
    float s = 0.f;
    for (int k = 0; k < 64; ++k) s += red[k];
    sm[SM_EOFF] = s;
  }
}

extern "C" void kernel_launch(void* const* d_in, const int* in_sizes, int n_in,
                              void* d_out, int out_size, void* d_ws, size_t ws_size,
                              hipStream_t stream) {
  const float* x     = (const float*)d_in[0];
  const float* gn0_w = (const float*)d_in[1];
  const float* gn0_b = (const float*)d_in[2];
  const float* gn0_ms= (const float*)d_in[3];
  const float* W1    = (const float*)d_in[4];
  const float* b1    = (const float*)d_in[5];
  const float* a1    = (const float*)d_in[6];
  const float* gn1_w = (const float*)d_in[7];
  const float* gn1_b = (const float*)d_in[8];
  const float* gn1_ms= (const float*)d_in[9];
  const float* W2    = (const float*)d_in[10];
  const float* b2    = (const float*)d_in[11];
  const float* a2    = (const float*)d_in[12];
  const float* gn2_w = (const float*)d_in[13];
  const float* gn2_b = (const float*)d_in[14];
  const float* gn2_ms= (const float*)d_in[15];
  const float* W3    = (const float*)d_in[16];
  const float* b3    = (const float*)d_in[17];
  const float* gn3_w = (const float*)d_in[18];
  const float* gn3_b = (const float*)d_in[19];
  const float* gn3_ms= (const float*)d_in[20];
  const float* Wih   = (const float*)d_in[21];
  const float* Whh   = (const float*)d_in[22];
  const float* bih   = (const float*)d_in[23];
  const float* bhh   = (const float*)d_in[24];
  const int*   eidx  = (const int*)d_in[25];
  const int* esrc = eidx;
  const int* edst = eidx + NE;

  float* sm   = (float*)d_ws;
  int* gcursor= (int*)(sm + SM_GCUR);          // 392 ints, zeroed by memset (counts)
  float* dinv = sm + OFF_DINV;
  float* h    = sm + OFF_H;
  unsigned* stage = (unsigned*)(sm + OFF_H);   // aliases h; dead before first gather
  uint4* hb4  = (uint4*)(sm + OFF_H);          // aliases h; written only after h is dead
  unsigned* y32 = (unsigned*)(sm + OFF_Y32);
  const uint4* y4 = (const uint4*)y32;
  float* part = sm + OFF_PART;
  int* col    = (int*)(sm + OFF_INT);          // NE
  int* rowptr = col + NE;                      // NPAD (NN+1)
  int* boff   = rowptr + NPAD;                 // NBUK+1
  float* out  = (float*)d_out;

  hipMemsetAsync(sm, 0, SM_ZEND * sizeof(float), stream);

  // CSR build (separate small kernels; fused gn0 stats)
  k_bin<<<NTILES, 256, 0, stream>>>(esrc, edst, x, gcursor, stage,
                                    sm + SM_SUMS(0), sm + SM_SUMSQ(0));
  k_bscan<<<1, 512, 0, stream>>>(gcursor, boff, rowptr);
  k_bsort<<<NBUK, 256, 0, stream>>>(stage, boff, col, rowptr, dinv);

  // layer 1
  k_mm<4><<<1024, 256, 0, stream>>>(x, W1, gn0_w, gn0_b, gn0_ms,
                                    sm + SM_SUMS(0), sm + SM_SUMSQ(0), dinv, y32);
  k_gather_fin<true, false><<<2048, 256, 0, stream>>>(y4, rowptr, col, dinv, b1, a1, h, nullptr,
                                                      sm + SM_SUMS(1), sm + SM_SUMSQ(1));
  // layer 2
  k_mm<64><<<1024, 256, 0, stream>>>(h, W2, gn1_w, gn1_b, gn1_ms,
                                     sm + SM_SUMS(1), sm + SM_SUMSQ(1), dinv, y32);
  k_gather_fin<true, false><<<2048, 256, 0, stream>>>(y4, rowptr, col, dinv, b2, a2, h, nullptr,
                                                      sm + SM_SUMS(2), sm + SM_SUMSQ(2));
  // layer 3 (no prelu): writes bf16 h copy only
  k_mm<64><<<1024, 256, 0, stream>>>(h, W3, gn2_w, gn2_b, gn2_ms,
                                     sm + SM_SUMS(2), sm + SM_SUMSQ(2), dinv, y32);
  k_gather_fin<false, true><<<2048, 256, 0, stream>>>(y4, rowptr, col, dinv, b3, nullptr, nullptr, hb4,
                                                      sm + SM_SUMS(3), sm + SM_SUMSQ(3));

  // Set2Set: boot LSTM (q*=0) + hv, then 3 steps
  k_attfin<<<1, 256, 0, stream>>>(part, gn3_w, gn3_b, gn3_ms,
                                  sm + SM_SUMS(3), sm + SM_SUMSQ(3),
                                  Wih, Whh, bih, bhh, sm, nullptr, 0);
  for (int s = 0; s < 3; ++s) {
    k_att<<<NB_ATT, 256, 0, stream>>>(hb4, sm, part);
    k_attfin<<<1, 256, 0, stream>>>(part, gn3_w, gn3_b, gn3_ms,
                                    sm + SM_SUMS(3), sm + SM_SUMSQ(3),
                                    Wih, Whh, bih, bhh, sm,
                                    (s == 2) ? out : nullptr, (s == 2) ? 2 : 1);
  }
}

// Round 10
// 493.381 us; speedup vs baseline: 1.7684x; 1.7160x over previous
//
#include <hip/hip_runtime.h>

#define NN 100000
#define NE 1600000
#define HID 64
#define EPSV 1e-5f
#define NB_ATT 256
#define NGRP 12500               // NN/8 node-groups for slice gather

// bucketed CSR build
#define NBUK 391                 // ceil(NN/256), bucket = dst>>8
#define BCAP 4608                // slots per bucket (lambda~4092, +8 sigma)
#define BTILE 4096               // edges per bin tile
#define NTILES 391               // ceil(NE/BTILE)

// ---------- small scratch layout (float indices into ws) ----------
#define SM_SUMS(l)  ((l)*128)
#define SM_SUMSQ(l) ((l)*128 + 64)
#define SM_HS       512
#define SM_C        576
#define SM_HV       768          // 64 floats
#define SM_EOFF     832
#define SM_GCUR     1024         // 392 ints (zeroed by memset)
#define SM_ZEND     1424         // memset covers [0, SM_ZEND)

// big buffers (float offsets)
#define NPAD        100352L
#define OFF_DINV    1424L
#define OFF_H       (OFF_DINV + NPAD)       // 6.4M floats; stage AND hb alias this region
#define OFF_Y32     (OFF_H + 6400000L)      // 3.2M uints (bf16x2), PLANE-major: 8 x NN x 16B
#define OFF_PART    (OFF_Y32 + 3200000L)    // NB_ATT*68
#define OFF_INT     (OFF_PART + 69632L)

static __device__ __forceinline__ unsigned bf16rne(float f) {
  unsigned u = __float_as_uint(f);
  return (u + 0x7fffu + ((u >> 16) & 1u)) >> 16;
}
static __device__ __forceinline__ unsigned packbf2(float lo, float hi) {
  return bf16rne(lo) | (bf16rne(hi) << 16);
}
static __device__ __forceinline__ float bflo(unsigned w) { return __uint_as_float(w << 16); }
static __device__ __forceinline__ float bfhi(unsigned w) { return __uint_as_float(w & 0xffff0000u); }

// GraphNorm affine from accumulated sums: gn(x) = sc*x + sh  (per feature j)
static __device__ __forceinline__ void gn_affine(int j, const float* w, const float* b,
                                                 const float* ms, const float* sums,
                                                 const float* sumsq, float& sc, float& sh) {
  const float invn = 1.0f / (float)NN;
  float mean = sums[j] * invn;
  float ex2  = sumsq[j] * invn;
  float m    = ms[j];
  float var  = ex2 - m * mean * mean * (2.0f - m);
  sc = w[j] * rsqrtf(var + EPSV);
  sh = b[j] - sc * m * mean;
}

// ---------------- pass 1: bin edges into per-bucket staging + gn0 stats ----------------
__global__ __launch_bounds__(256) void k_bin(const int* __restrict__ src, const int* __restrict__ dst,
                                             const float* __restrict__ x,
                                             int* __restrict__ gcursor, unsigned* __restrict__ stage,
                                             float* __restrict__ sums0, float* __restrict__ sumsq0) {
  __shared__ int hist[NBUK], base[NBUK];
  int t = threadIdx.x, lane = t & 63;
  long tile0 = (long)blockIdx.x * BTILE;
  for (int b = t; b < NBUK; b += 256) hist[b] = 0;
  __syncthreads();
  unsigned v[16]; int bk[16];
#pragma unroll
  for (int k = 0; k < 16; ++k) {
    long e = tile0 + k * 256 + t;
    if (e < NE) {
      int d = dst[e], s = src[e];
      bk[k] = d >> 8;
      v[k] = ((unsigned)(d & 255) << 24) | (unsigned)s;
      atomicAdd(&hist[bk[k]], 1);
    } else bk[k] = -1;
  }
  __syncthreads();
  for (int b = t; b < NBUK; b += 256) {
    int c = hist[b];
    base[b] = c ? atomicAdd(&gcursor[b], c) : 0;
    hist[b] = 0;
  }
  __syncthreads();
#pragma unroll
  for (int k = 0; k < 16; ++k) {
    if (bk[k] >= 0) {
      int bkk = bk[k];
      int off = atomicAdd(&hist[bkk], 1);
      stage[(long)bkk * BCAP + base[bkk] + off] = v[k];
    }
  }
  // gn0 stats over x
  const float4* x4 = (const float4*)x;
  float4 s4 = make_float4(0.f, 0.f, 0.f, 0.f);
  float4 q4 = make_float4(0.f, 0.f, 0.f, 0.f);
  int stride = gridDim.x * 256;
  for (int i = blockIdx.x * 256 + t; i < NN; i += stride) {
    float4 xv = x4[i];
    s4.x += xv.x; s4.y += xv.y; s4.z += xv.z; s4.w += xv.w;
    q4.x += xv.x * xv.x; q4.y += xv.y * xv.y; q4.z += xv.z * xv.z; q4.w += xv.w * xv.w;
  }
#pragma unroll
  for (int off = 32; off; off >>= 1) {
    s4.x += __shfl_xor(s4.x, off, 64); s4.y += __shfl_xor(s4.y, off, 64);
    s4.z += __shfl_xor(s4.z, off, 64); s4.w += __shfl_xor(s4.w, off, 64);
    q4.x += __shfl_xor(q4.x, off, 64); q4.y += __shfl_xor(q4.y, off, 64);
    q4.z += __shfl_xor(q4.z, off, 64); q4.w += __shfl_xor(q4.w, off, 64);
  }
  if (lane == 0) {
    atomicAdd(&sums0[0], s4.x); atomicAdd(&sums0[1], s4.y);
    atomicAdd(&sums0[2], s4.z); atomicAdd(&sums0[3], s4.w);
    atomicAdd(&sumsq0[0], q4.x); atomicAdd(&sumsq0[1], q4.y);
    atomicAdd(&sumsq0[2], q4.z); atomicAdd(&sumsq0[3], q4.w);
  }
}

// ---------------- pass 1b: scan bucket counts -> boff ----------------
__global__ __launch_bounds__(512) void k_bscan(const int* __restrict__ gcursor,
                                               int* __restrict__ boff, int* __restrict__ rowptr) {
  __shared__ int ws[8];
  int t = threadIdx.x, lane = t & 63;
  int c = (t < NBUK) ? gcursor[t] : 0;
  int incl = c;
#pragma unroll
  for (int off = 1; off < 64; off <<= 1) {
    int u = __shfl_up(incl, off, 64);
    if (lane >= off) incl += u;
  }
  if (lane == 63) ws[t >> 6] = incl;
  __syncthreads();
  if (t == 0) {
    int s = 0;
#pragma unroll
    for (int w = 0; w < 8; ++w) { int tv = ws[w]; ws[w] = s; s += tv; }
  }
  __syncthreads();
  if (t < NBUK) boff[t] = incl - c + ws[t >> 6];
  if (t == 0) { boff[NBUK] = NE; rowptr[NN] = NE; }
}

// ---------------- pass 2: per-bucket counting sort -> col, rowptr, dinv ----------------
__global__ __launch_bounds__(256) void k_bsort(const unsigned* __restrict__ stage,
                                               const int* __restrict__ boff,
                                               int* __restrict__ col, int* __restrict__ rowptr,
                                               float* __restrict__ dinv) {
  __shared__ int hist[256], cur[256];
  __shared__ int ws[4];
  int b = blockIdx.x;
  int t = threadIdx.x, lane = t & 63;
  long sb = (long)b * BCAP;
  int b0 = boff[b], cb = boff[b + 1] - b0;
  hist[t] = 0;
  __syncthreads();
  for (int j = t; j < cb; j += 256)
    atomicAdd(&hist[stage[sb + j] >> 24], 1);
  __syncthreads();
  int c = hist[t];
  int incl = c;
#pragma unroll
  for (int off = 1; off < 64; off <<= 1) {
    int u = __shfl_up(incl, off, 64);
    if (lane >= off) incl += u;
  }
  if (lane == 63) ws[t >> 6] = incl;
  __syncthreads();
  int woff = 0;
  if (t >= 64) woff += ws[0];
  if (t >= 128) woff += ws[1];
  if (t >= 192) woff += ws[2];
  int gbase = b0 + (incl - c) + woff;
  int node = b * 256 + t;
  if (node < NN) {
    rowptr[node] = gbase;
    dinv[node] = rsqrtf((float)c + 1.0f);
  }
  cur[t] = gbase;
  __syncthreads();
  for (int j = t; j < cb; j += 256) {
    unsigned v = stage[sb + j];
    int pos = atomicAdd(&cur[v >> 24], 1);
    col[pos] = (int)(v & 0xffffffu);
  }
}

// ---------------- fused GraphNorm-apply + matmul + dinv prescale -> bf16 y (PLANE-major) ----------------
// Plane p holds features 8p..8p+7 of all nodes: contiguous 1.6MB => per-slice L2 residency.
template <int D>
__global__ __launch_bounds__(256) void k_mm(const float* __restrict__ hin, const float* __restrict__ W,
                                            const float* __restrict__ gw, const float* __restrict__ gb,
                                            const float* __restrict__ gms,
                                            const float* __restrict__ sums, const float* __restrict__ sumsq,
                                            const float* __restrict__ dinv,
                                            unsigned* __restrict__ y32) {
  __shared__ float4 Ws4[D][16];
  __shared__ float4 woff4[16];
  __shared__ float scale[D], shift[D];
  __shared__ float hl[16][68];      // stride 68: 16B-aligned rows, bank-shift 4
  int t = threadIdx.x;
  if (t < D) {
    float sc, sh;
    gn_affine(t, gw, gb, gms, sums, sumsq, sc, sh);
    scale[t] = sc; shift[t] = sh;
  }
  __syncthreads();
  for (int idx = t; idx < D * 64; idx += 256) {
    int k = idx >> 6;
    ((float*)Ws4)[idx] = scale[k] * W[idx];
  }
  __syncthreads();
  if (t < 64) {
    float o = 0.f;
#pragma unroll
    for (int k = 0; k < D; ++k) o += shift[k] * W[k * 64 + t];
    ((float*)woff4)[t] = o;
  }
  __syncthreads();

  int row = t >> 4, cg = t & 15;
  const int nG = NN / 16;  // 6250, exact
  for (int g = blockIdx.x; g < nG; g += gridDim.x) {
    if (D == 64) {
      *(float4*)&hl[row][cg * 4] = *(const float4*)(hin + (long)(g * 16 + row) * 64 + cg * 4);
    } else {
      if (t < 64) hl[t >> 2][t & 3] = hin[g * 64 + t];
    }
    __syncthreads();
    float4 acc = woff4[cg];
#pragma unroll
    for (int k = 0; k < D; ++k) {
      float hk = hl[row][k];
      float4 w4 = Ws4[k][cg];
      acc.x += hk * w4.x; acc.y += hk * w4.y;
      acc.z += hk * w4.z; acc.w += hk * w4.w;
    }
    int node = g * 16 + row;
    float di = dinv[node];
    uint2 u;
    u.x = packbf2(di * acc.x, di * acc.y);
    u.y = packbf2(di * acc.z, di * acc.w);
    // plane-major: plane = cg>>1, half = cg&1
    *(uint2*)(y32 + ((long)(cg >> 1) * NN + node) * 4 + (cg & 1) * 2) = u;
    __syncthreads();
  }
}

// ---------------- XCD-sliced CSR gather (plane-major y) ----------------
// Block handles feature slice s = blockIdx&7; under round-robin blockIdx->XCD mapping all
// slice-s blocks share one XCD; slice plane = contiguous 1.6MB -> L2-resident.
#define ACCW(WV) { f[0]+=bflo(WV.x); f[1]+=bfhi(WV.x); f[2]+=bflo(WV.y); f[3]+=bfhi(WV.y); \
                   f[4]+=bflo(WV.z); f[5]+=bfhi(WV.z); f[6]+=bflo(WV.w); f[7]+=bfhi(WV.w); }

template <bool PR, bool HB>
__global__ __launch_bounds__(256) void k_gather_fin(const uint4* __restrict__ y4x,
                                                    const int* __restrict__ rowptr, const int* __restrict__ col,
                                                    const float* __restrict__ dinv,
                                                    const float* __restrict__ b, const float* __restrict__ a,
                                                    float* __restrict__ h, uint4* __restrict__ hb4,
                                                    float* __restrict__ sums, float* __restrict__ sumsq) {
  __shared__ float ssum[8], ssq[8];
  int t = threadIdx.x, lane = t & 63, w = t >> 6;
  int n = lane >> 3, j = lane & 7;
  int s = blockIdx.x & 7;
  const uint4* yp = y4x + (long)s * NN;   // this slice's plane
  if (t < 8) { ssum[t] = 0.f; ssq[t] = 0.f; }
  __syncthreads();
  float bv[8], av[8];
#pragma unroll
  for (int k = 0; k < 8; ++k) {
    bv[k] = b[8 * s + k];
    av[k] = PR ? a[8 * s + k] : 1.f;
  }
  float sa[8] = {0,0,0,0,0,0,0,0}, qa[8] = {0,0,0,0,0,0,0,0};
  int gstride = (gridDim.x >> 3) * 4;
  for (int g = (blockIdx.x >> 3) * 4 + w; g < NGRP; g += gstride) {
    int i0 = g * 8;
    int r = (lane < 9) ? rowptr[i0 + lane] : 0;
    int p0 = __shfl(r, n, 64);
    int p1 = __shfl(r, n + 1, 64);
    float f[8] = {0,0,0,0,0,0,0,0};
    for (int p = p0 + j; p < p1; p += 8) {
      int c = col[p];
      uint4 wv = yp[c];
      ACCW(wv);
    }
    if (((p1 - p0) & 7) == j) {           // self-loop: exactly one lane per node
      uint4 wv = yp[i0 + n];
      ACCW(wv);
    }
#pragma unroll
    for (int k = 0; k < 8; ++k) {
      float v = f[k];
      v += __shfl_xor(v, 1, 64);
      v += __shfl_xor(v, 2, 64);
      v += __shfl_xor(v, 4, 64);
      f[k] = v;
    }
    if (j == 0) {
      int i = i0 + n;
      float di = dinv[i];
      float vo[8];
#pragma unroll
      for (int k = 0; k < 8; ++k) {
        float v = di * f[k] + bv[k];
        if (PR && v < 0.f) v *= av[k];
        vo[k] = v;
        sa[k] += v; qa[k] += v * v;
      }
      if (HB) {
        uint4 u;
        u.x = packbf2(vo[0], vo[1]); u.y = packbf2(vo[2], vo[3]);
        u.z = packbf2(vo[4], vo[5]); u.w = packbf2(vo[6], vo[7]);
        hb4[(long)i * 8 + s] = u;
      } else {
        *(float4*)(h + (long)i * 64 + 8 * s)     = make_float4(vo[0], vo[1], vo[2], vo[3]);
        *(float4*)(h + (long)i * 64 + 8 * s + 4) = make_float4(vo[4], vo[5], vo[6], vo[7]);
      }
    }
  }
  if (j == 0) {
#pragma unroll
    for (int k = 0; k < 8; ++k) { atomicAdd(&ssum[k], sa[k]); atomicAdd(&ssq[k], qa[k]); }
  }
  __syncthreads();
  if (t < 8) {
    atomicAdd(&sums[8 * s + t], ssum[t]);
    atomicAdd(&sumsq[8 * s + t], ssq[t]);
  }
}

// ---------------- Set2Set: fused attention pass (bf16 h, 8-lane groups) ----------------
__global__ __launch_bounds__(256) void k_att(const uint4* __restrict__ hb4, const float* __restrict__ sm,
                                             float* __restrict__ part) {
  __shared__ float gm[32], gz[32], gr[32][64];
  int t = threadIdx.x;
  int grp = t >> 3, l7 = t & 7;
  float hvr[8];
#pragma unroll
  for (int k = 0; k < 8; ++k) hvr[k] = sm[SM_HV + 8 * l7 + k];
  float eoff = sm[SM_EOFF];
  float m = -3.4e38f, z = 0.f;
  float r[8] = {0,0,0,0,0,0,0,0};
  int ngrp = gridDim.x * 32;
  for (int i = blockIdx.x * 32 + grp; i < NN; i += ngrp) {
    uint4 hw = hb4[(long)i * 8 + l7];
    float hx[8] = { bflo(hw.x), bfhi(hw.x), bflo(hw.y), bfhi(hw.y),
                    bflo(hw.z), bfhi(hw.z), bflo(hw.w), bfhi(hw.w) };
    float dot = 0.f;
#pragma unroll
    for (int k = 0; k < 8; ++k) dot += hx[k] * hvr[k];
    dot += __shfl_xor(dot, 1, 64);
    dot += __shfl_xor(dot, 2, 64);
    dot += __shfl_xor(dot, 4, 64);
    float e = dot + eoff;
    float mn = fmaxf(m, e);
    float sc = expf(m - mn);
    float pb = expf(e - mn);
    z = z * sc + pb;
#pragma unroll
    for (int k = 0; k < 8; ++k) r[k] = r[k] * sc + pb * hx[k];
    m = mn;
  }
#pragma unroll
  for (int k = 0; k < 8; ++k) gr[grp][8 * l7 + k] = r[k];
  if (l7 == 0) { gm[grp] = m; gz[grp] = z; }
  __syncthreads();
  if (t < 64) {
    float mb = gm[0];
#pragma unroll
    for (int k = 1; k < 32; ++k) mb = fmaxf(mb, gm[k]);
    float rb = 0.f, zb = 0.f;
#pragma unroll 8
    for (int k = 0; k < 32; ++k) {
      float scl = expf(gm[k] - mb);
      rb += gr[k][t] * scl;
      zb += gz[k] * scl;
    }
    part[blockIdx.x * 68 + t] = rb;
    if (t == 0) { part[blockIdx.x * 68 + 64] = mb; part[blockIdx.x * 68 + 65] = zb; }
  }
}

// ---------------- Set2Set finish: reduce partials -> q_star -> LSTM(next) -> hv ----------------
// mode 0: boot (no reduce; LSTM from q*=0), 1: mid step, 2: final (write out, no LSTM)
__global__ __launch_bounds__(256) void k_attfin(const float* __restrict__ part,
                                                const float* __restrict__ gw, const float* __restrict__ gb,
                                                const float* __restrict__ gms,
                                                const float* __restrict__ sums, const float* __restrict__ sumsq,
                                                const float* __restrict__ Wih, const float* __restrict__ Whh,
                                                const float* __restrict__ bih, const float* __restrict__ bhh,
                                                float* __restrict__ sm, float* __restrict__ out, int mode) {
  __shared__ float hsL[64], cL[64], qsL[128], gL[256], red[256], sf[NB_ATT], rr4[4][64];
  int t = threadIdx.x, lane = t & 63, w = t >> 6;
  if (t < 64) { hsL[t] = sm[SM_HS + t]; cL[t] = sm[SM_C + t]; }
  __syncthreads();
  if (mode > 0) {
    float mv = part[t * 68 + 64];
    red[t] = mv; __syncthreads();
    for (int s = 128; s; s >>= 1) { if (t < s) red[t] = fmaxf(red[t], red[t + s]); __syncthreads(); }
    float mg = red[0];
    __syncthreads();
    float sc_ = expf(mv - mg);
    sf[t] = sc_;
    red[t] = part[t * 68 + 65] * sc_; __syncthreads();
    for (int s = 128; s; s >>= 1) { if (t < s) red[t] += red[t + s]; __syncthreads(); }
    float zg = red[0];
    __syncthreads();
    float racc = 0.f;
#pragma unroll 8
    for (int jx = 0; jx < 64; ++jx) {
      int bk = 4 * jx + w;
      racc += part[bk * 68 + lane] * sf[bk];
    }
    rr4[w][lane] = racc;
    __syncthreads();
    if (t < 64) {
      float rg = rr4[0][t] + rr4[1][t] + rr4[2][t] + rr4[3][t];
      float sc, sh;
      gn_affine(t, gw, gb, gms, sums, sumsq, sc, sh);
      float rr = sc * (rg / zg) + sh;
      qsL[t] = hsL[t]; qsL[64 + t] = rr;
      if (mode == 2) { out[t] = hsL[t]; out[64 + t] = rr; }
    }
  } else {
    if (t < 64) { qsL[t] = 0.f; qsL[64 + t] = 0.f; hsL[t] = 0.f; cL[t] = 0.f; }
  }
  __syncthreads();
  if (mode == 2) return;
  float g = bih[t] + bhh[t];
#pragma unroll 16
  for (int k = 0; k < 128; ++k) g += qsL[k] * Wih[t * 128 + k];
#pragma unroll 16
  for (int k = 0; k < 64; ++k) g += hsL[k] * Whh[t * 64 + k];
  gL[t] = g;
  __syncthreads();
  if (t < 64) {
    float ig = 1.f / (1.f + expf(-gL[t]));
    float fg = 1.f / (1.f + expf(-gL[64 + t]));
    float gg = tanhf(gL[128 + t]);
    float og = 1.f / (1.f + expf(-gL[192 + t]));
    float c = fg * cL[t] + ig * gg;
    float hsn = og * tanhf(c);
    sm[SM_C + t] = c;
    sm[SM_HS + t] = hsn;
    float sc, sh;
    gn_affine(t, gw, gb, gms, sums, sumsq, sc, sh);
    sm[SM_HV + t] = sc * hsn;
    red[t] = sh * hsn;
  }
  __syncthreads();
  if (t == 0) {
    float s = 0.f;
    for (int k = 0; k < 64; ++k) s += red[k];
    sm[SM_EOFF] = s;
  }
}

extern "C" void kernel_launch(void* const* d_in, const int* in_sizes, int n_in,
                              void* d_out, int out_size, void* d_ws, size_t ws_size,
                              hipStream_t stream) {
  const float* x     = (const float*)d_in[0];
  const float* gn0_w = (const float*)d_in[1];
  const float* gn0_b = (const float*)d_in[2];
  const float* gn0_ms= (const float*)d_in[3];
  const float* W1    = (const float*)d_in[4];
  const float* b1    = (const float*)d_in[5];
  const float* a1    = (const float*)d_in[6];
  const float* gn1_w = (const float*)d_in[7];
  const float* gn1_b = (const float*)d_in[8];
  const float* gn1_ms= (const float*)d_in[9];
  const float* W2    = (const float*)d_in[10];
  const float* b2    = (const float*)d_in[11];
  const float* a2    = (const float*)d_in[12];
  const float* gn2_w = (const float*)d_in[13];
  const float* gn2_b = (const float*)d_in[14];
  const float* gn2_ms= (const float*)d_in[15];
  const float* W3    = (const float*)d_in[16];
  const float* b3    = (const float*)d_in[17];
  const float* gn3_w = (const float*)d_in[18];
  const float* gn3_b = (const float*)d_in[19];
  const float* gn3_ms= (const float*)d_in[20];
  const float* Wih   = (const float*)d_in[21];
  const float* Whh   = (const float*)d_in[22];
  const float* bih   = (const float*)d_in[23];
  const float* bhh   = (const float*)d_in[24];
  const int*   eidx  = (const int*)d_in[25];
  const int* esrc = eidx;
  const int* edst = eidx + NE;

  float* sm   = (float*)d_ws;
  int* gcursor= (int*)(sm + SM_GCUR);          // 392 ints, zeroed by memset (counts)
  float* dinv = sm + OFF_DINV;
  float* h    = sm + OFF_H;
  unsigned* stage = (unsigned*)(sm + OFF_H);   // aliases h; dead before first gather
  uint4* hb4  = (uint4*)(sm + OFF_H);          // aliases h; written only after h is dead
  unsigned* y32 = (unsigned*)(sm + OFF_Y32);
  const uint4* y4 = (const uint4*)y32;
  float* part = sm + OFF_PART;
  int* col    = (int*)(sm + OFF_INT);          // NE
  int* rowptr = col + NE;                      // NPAD (NN+1)
  int* boff   = rowptr + NPAD;                 // NBUK+1
  float* out  = (float*)d_out;

  hipMemsetAsync(sm, 0, SM_ZEND * sizeof(float), stream);

  // CSR build (fused gn0 stats)
  k_bin<<<NTILES, 256, 0, stream>>>(esrc, edst, x, gcursor, stage,
                                    sm + SM_SUMS(0), sm + SM_SUMSQ(0));
  k_bscan<<<1, 512, 0, stream>>>(gcursor, boff, rowptr);
  k_bsort<<<NBUK, 256, 0, stream>>>(stage, boff, col, rowptr, dinv);

  // layer 1
  k_mm<4><<<1024, 256, 0, stream>>>(x, W1, gn0_w, gn0_b, gn0_ms,
                                    sm + SM_SUMS(0), sm + SM_SUMSQ(0), dinv, y32);
  k_gather_fin<true, false><<<2048, 256, 0, stream>>>(y4, rowptr, col, dinv, b1, a1, h, nullptr,
                                                      sm + SM_SUMS(1), sm + SM_SUMSQ(1));
  // layer 2
  k_mm<64><<<1024, 256, 0, stream>>>(h, W2, gn1_w, gn1_b, gn1_ms,
                                     sm + SM_SUMS(1), sm + SM_SUMSQ(1), dinv, y32);
  k_gather_fin<true, false><<<2048, 256, 0, stream>>>(y4, rowptr, col, dinv, b2, a2, h, nullptr,
                                                      sm + SM_SUMS(2), sm + SM_SUMSQ(2));
  // layer 3 (no prelu): writes bf16 h copy only
  k_mm<64><<<1024, 256, 0, stream>>>(h, W3, gn2_w, gn2_b, gn2_ms,
                                     sm + SM_SUMS(2), sm + SM_SUMSQ(2), dinv, y32);
  k_gather_fin<false, true><<<2048, 256, 0, stream>>>(y4, rowptr, col, dinv, b3, nullptr, nullptr, hb4,
                                                      sm + SM_SUMS(3), sm + SM_SUMSQ(3));

  // Set2Set: boot LSTM (q*=0) + hv, then 3 steps
  k_attfin<<<1, 256, 0, stream>>>(part, gn3_w, gn3_b, gn3_ms,
                                  sm + SM_SUMS(3), sm + SM_SUMSQ(3),
                                  Wih, Whh, bih, bhh, sm, nullptr, 0);
  for (int s = 0; s < 3; ++s) {
    k_att<<<NB_ATT, 256, 0, stream>>>(hb4, sm, part);
    k_attfin<<<1, 256, 0, stream>>>(part, gn3_w, gn3_b, gn3_ms,
                                    sm + SM_SUMS(3), sm + SM_SUMSQ(3),
                                    Wih, Whh, bih, bhh, sm,
                                    (s == 2) ? out : nullptr, (s == 2) ? 2 : 1);
  }
}

// Round 11
// 433.099 us; speedup vs baseline: 2.0146x; 1.1392x over previous
//
#include <hip/hip_runtime.h>

#define NN 100000
#define NE 1600000
#define HID 64
#define EPSV 1e-5f
#define NB_ATT 512
#define NGRP 12500               // NN/8 node-groups for slice gather

// bucketed CSR build
#define NBUK 391                 // ceil(100000/256), bucket = dst>>8
#define BCAP 4608                // slots per bucket (lambda~4092, +8 sigma)
#define BTILE 2048               // edges per bin tile
#define NTILES 782               // ceil(NE/BTILE)

// ---------- small scratch layout (float indices into ws) ----------
#define SM_SUMS(l)  ((l)*128)
#define SM_SUMSQ(l) ((l)*128 + 64)
#define SM_HS       512
#define SM_C        576
#define SM_HV       768          // 64 floats
#define SM_EOFF     832
#define SM_GCUR     1024         // 392 ints (zeroed by memset)
#define SM_ZEND     1424         // memset covers [0, SM_ZEND)
#define SM_GPART    1424         // 782*8 floats, all written before read (no zero needed)

// big buffers (float offsets)
#define NPAD        100352L
#define OFF_DINV    7684L
#define OFF_H       (OFF_DINV + NPAD)       // 6.4M floats; stage AND hb alias this region
#define OFF_Y32     (OFF_H + 6400000L)      // 3.2M uints (bf16x2), PLANE-major: 8 x NN x 16B
#define OFF_PART    (OFF_Y32 + 3200000L)    // NB_ATT*68
#define OFF_INT     (OFF_PART + 69632L)

static __device__ __forceinline__ unsigned bf16rne(float f) {
  unsigned u = __float_as_uint(f);
  return (u + 0x7fffu + ((u >> 16) & 1u)) >> 16;
}
static __device__ __forceinline__ unsigned packbf2(float lo, float hi) {
  return bf16rne(lo) | (bf16rne(hi) << 16);
}
static __device__ __forceinline__ float bflo(unsigned w) { return __uint_as_float(w << 16); }
static __device__ __forceinline__ float bfhi(unsigned w) { return __uint_as_float(w & 0xffff0000u); }

// GraphNorm affine from accumulated sums: gn(x) = sc*x + sh  (per feature j)
static __device__ __forceinline__ void gn_affine(int j, const float* w, const float* b,
                                                 const float* ms, const float* sums,
                                                 const float* sumsq, float& sc, float& sh) {
  const float invn = 1.0f / (float)NN;
  float mean = sums[j] * invn;
  float ex2  = sumsq[j] * invn;
  float m    = ms[j];
  float var  = ex2 - m * mean * mean * (2.0f - m);
  sc = w[j] * rsqrtf(var + EPSV);
  sh = b[j] - sc * m * mean;
}

// ---------------- pass 1: bin edges into per-bucket staging + gn0 block partials ----------------
// NO global same-line atomics for stats: per-block partial -> gpart (reduced in k_bscan).
__global__ __launch_bounds__(256) void k_bin(const int* __restrict__ src, const int* __restrict__ dst,
                                             const float* __restrict__ x,
                                             int* __restrict__ gcursor, unsigned* __restrict__ stage,
                                             float* __restrict__ gpart) {
  __shared__ int hist[NBUK], base[NBUK];
  __shared__ float gred[4][8];
  int t = threadIdx.x, lane = t & 63, w = t >> 6;
  long tile0 = (long)blockIdx.x * BTILE;
  for (int b = t; b < NBUK; b += 256) hist[b] = 0;
  __syncthreads();
  unsigned v[8]; int bk[8];
#pragma unroll
  for (int k = 0; k < 8; ++k) {
    long e = tile0 + k * 256 + t;
    if (e < NE) {
      int d = dst[e], s = src[e];
      bk[k] = d >> 8;
      v[k] = ((unsigned)(d & 255) << 24) | (unsigned)s;
      atomicAdd(&hist[bk[k]], 1);
    } else bk[k] = -1;
  }
  __syncthreads();
  for (int b = t; b < NBUK; b += 256) {
    int c = hist[b];
    base[b] = c ? atomicAdd(&gcursor[b], c) : 0;
    hist[b] = 0;
  }
  __syncthreads();
#pragma unroll
  for (int k = 0; k < 8; ++k) {
    if (bk[k] >= 0) {
      int bkk = bk[k];
      int off = atomicAdd(&hist[bkk], 1);
      stage[(long)bkk * BCAP + base[bkk] + off] = v[k];
    }
  }
  // gn0 stats over x -> per-block partial (no atomics)
  const float4* x4 = (const float4*)x;
  float4 s4 = make_float4(0.f, 0.f, 0.f, 0.f);
  float4 q4 = make_float4(0.f, 0.f, 0.f, 0.f);
  int stride = gridDim.x * 256;
  for (int i = blockIdx.x * 256 + t; i < NN; i += stride) {
    float4 xv = x4[i];
    s4.x += xv.x; s4.y += xv.y; s4.z += xv.z; s4.w += xv.w;
    q4.x += xv.x * xv.x; q4.y += xv.y * xv.y; q4.z += xv.z * xv.z; q4.w += xv.w * xv.w;
  }
#pragma unroll
  for (int off = 32; off; off >>= 1) {
    s4.x += __shfl_xor(s4.x, off, 64); s4.y += __shfl_xor(s4.y, off, 64);
    s4.z += __shfl_xor(s4.z, off, 64); s4.w += __shfl_xor(s4.w, off, 64);
    q4.x += __shfl_xor(q4.x, off, 64); q4.y += __shfl_xor(q4.y, off, 64);
    q4.z += __shfl_xor(q4.z, off, 64); q4.w += __shfl_xor(q4.w, off, 64);
  }
  if (lane == 0) {
    gred[w][0] = s4.x; gred[w][1] = s4.y; gred[w][2] = s4.z; gred[w][3] = s4.w;
    gred[w][4] = q4.x; gred[w][5] = q4.y; gred[w][6] = q4.z; gred[w][7] = q4.w;
  }
  __syncthreads();
  if (t < 8) gpart[blockIdx.x * 8 + t] = gred[0][t] + gred[1][t] + gred[2][t] + gred[3][t];
}

// ---------------- pass 1b: scan bucket counts -> boff; reduce gn0 partials ----------------
__global__ __launch_bounds__(512) void k_bscan(const int* __restrict__ gcursor,
                                               int* __restrict__ boff, int* __restrict__ rowptr,
                                               const float* __restrict__ gpart,
                                               float* __restrict__ sums0, float* __restrict__ sumsq0) {
  __shared__ int ws[8];
  __shared__ float gl[64][8];
  int t = threadIdx.x, lane = t & 63;
  int c = (t < NBUK) ? gcursor[t] : 0;
  int incl = c;
#pragma unroll
  for (int off = 1; off < 64; off <<= 1) {
    int u = __shfl_up(incl, off, 64);
    if (lane >= off) incl += u;
  }
  if (lane == 63) ws[t >> 6] = incl;
  __syncthreads();
  if (t == 0) {
    int s = 0;
#pragma unroll
    for (int w = 0; w < 8; ++w) { int tv = ws[w]; ws[w] = s; s += tv; }
  }
  __syncthreads();
  if (t < NBUK) boff[t] = incl - c + ws[t >> 6];
  if (t == 0) { boff[NBUK] = NE; rowptr[NN] = NE; }
  // gn0 partial reduce: 782 x 8 -> 8
  float acc = 0.f;
  int f = t & 7, r = t >> 3;            // 64 row-groups
  for (int i = r; i < NTILES; i += 64) acc += gpart[i * 8 + f];
  gl[r][f] = acc;
  __syncthreads();
  if (t < 8) {
    float s = 0.f;
#pragma unroll 16
    for (int rr = 0; rr < 64; ++rr) s += gl[rr][t];
    if (t < 4) sums0[t] = s;
    else sumsq0[t - 4] = s;
  }
}

// ---------------- pass 2: per-bucket counting sort -> col, rowptr, dinv ----------------
__global__ __launch_bounds__(256) void k_bsort(const unsigned* __restrict__ stage,
                                               const int* __restrict__ boff,
                                               int* __restrict__ col, int* __restrict__ rowptr,
                                               float* __restrict__ dinv) {
  __shared__ int hist[256], cur[256];
  __shared__ int ws[4];
  int b = blockIdx.x;
  int t = threadIdx.x, lane = t & 63;
  long sb = (long)b * BCAP;
  int b0 = boff[b], cb = boff[b + 1] - b0;
  hist[t] = 0;
  __syncthreads();
  for (int j = t; j < cb; j += 256)
    atomicAdd(&hist[stage[sb + j] >> 24], 1);
  __syncthreads();
  int c = hist[t];
  int incl = c;
#pragma unroll
  for (int off = 1; off < 64; off <<= 1) {
    int u = __shfl_up(incl, off, 64);
    if (lane >= off) incl += u;
  }
  if (lane == 63) ws[t >> 6] = incl;
  __syncthreads();
  int woff = 0;
  if (t >= 64) woff += ws[0];
  if (t >= 128) woff += ws[1];
  if (t >= 192) woff += ws[2];
  int gbase = b0 + (incl - c) + woff;
  int node = b * 256 + t;
  if (node < NN) {
    rowptr[node] = gbase;
    dinv[node] = rsqrtf((float)c + 1.0f);
  }
  cur[t] = gbase;
  __syncthreads();
  for (int j = t; j < cb; j += 256) {
    unsigned v = stage[sb + j];
    int pos = atomicAdd(&cur[v >> 24], 1);
    col[pos] = (int)(v & 0xffffffu);
  }
}

// ---------------- fused GraphNorm-apply + matmul + dinv prescale -> bf16 y (PLANE-major) ----------------
template <int D>
__global__ __launch_bounds__(256) void k_mm(const float* __restrict__ hin, const float* __restrict__ W,
                                            const float* __restrict__ gw, const float* __restrict__ gb,
                                            const float* __restrict__ gms,
                                            const float* __restrict__ sums, const float* __restrict__ sumsq,
                                            const float* __restrict__ dinv,
                                            unsigned* __restrict__ y32) {
  __shared__ float4 Ws4[D][16];
  __shared__ float4 woff4[16];
  __shared__ float scale[D], shift[D];
  __shared__ float hl[16][68];      // stride 68: 16B-aligned rows, bank-shift 4
  int t = threadIdx.x;
  if (t < D) {
    float sc, sh;
    gn_affine(t, gw, gb, gms, sums, sumsq, sc, sh);
    scale[t] = sc; shift[t] = sh;
  }
  __syncthreads();
  for (int idx = t; idx < D * 64; idx += 256) {
    int k = idx >> 6;
    ((float*)Ws4)[idx] = scale[k] * W[idx];
  }
  __syncthreads();
  if (t < 64) {
    float o = 0.f;
#pragma unroll
    for (int k = 0; k < D; ++k) o += shift[k] * W[k * 64 + t];
    ((float*)woff4)[t] = o;
  }
  __syncthreads();

  int row = t >> 4, cg = t & 15;
  const int nG = NN / 16;  // 6250, exact
  for (int g = blockIdx.x; g < nG; g += gridDim.x) {
    if (D == 64) {
      *(float4*)&hl[row][cg * 4] = *(const float4*)(hin + (long)(g * 16 + row) * 64 + cg * 4);
    } else {
      if (t < 64) hl[t >> 2][t & 3] = hin[g * 64 + t];
    }
    __syncthreads();
    float4 acc = woff4[cg];
#pragma unroll
    for (int k = 0; k < D; ++k) {
      float hk = hl[row][k];
      float4 w4 = Ws4[k][cg];
      acc.x += hk * w4.x; acc.y += hk * w4.y;
      acc.z += hk * w4.z; acc.w += hk * w4.w;
    }
    int node = g * 16 + row;
    float di = dinv[node];
    uint2 u;
    u.x = packbf2(di * acc.x, di * acc.y);
    u.y = packbf2(di * acc.z, di * acc.w);
    // plane-major: plane = cg>>1, half = cg&1
    *(uint2*)(y32 + ((long)(cg >> 1) * NN + node) * 4 + (cg & 1) * 2) = u;
    __syncthreads();
  }
}

// ---------------- XCD-sliced CSR gather (plane-major y) ----------------
#define ACCW(WV) { f[0]+=bflo(WV.x); f[1]+=bfhi(WV.x); f[2]+=bflo(WV.y); f[3]+=bfhi(WV.y); \
                   f[4]+=bflo(WV.z); f[5]+=bfhi(WV.z); f[6]+=bflo(WV.w); f[7]+=bfhi(WV.w); }

template <bool PR, bool HB>
__global__ __launch_bounds__(256) void k_gather_fin(const uint4* __restrict__ y4x,
                                                    const int* __restrict__ rowptr, const int* __restrict__ col,
                                                    const float* __restrict__ dinv,
                                                    const float* __restrict__ b, const float* __restrict__ a,
                                                    float* __restrict__ h, uint4* __restrict__ hb4,
                                                    float* __restrict__ sums, float* __restrict__ sumsq) {
  __shared__ float ssum[8], ssq[8];
  int t = threadIdx.x, lane = t & 63, w = t >> 6;
  int n = lane >> 3, j = lane & 7;
  int s = blockIdx.x & 7;
  const uint4* yp = y4x + (long)s * NN;   // this slice's plane
  if (t < 8) { ssum[t] = 0.f; ssq[t] = 0.f; }
  __syncthreads();
  float bv[8], av[8];
#pragma unroll
  for (int k = 0; k < 8; ++k) {
    bv[k] = b[8 * s + k];
    av[k] = PR ? a[8 * s + k] : 1.f;
  }
  float sa[8] = {0,0,0,0,0,0,0,0}, qa[8] = {0,0,0,0,0,0,0,0};
  int gstride = (gridDim.x >> 3) * 4;
  for (int g = (blockIdx.x >> 3) * 4 + w; g < NGRP; g += gstride) {
    int i0 = g * 8;
    int r = (lane < 9) ? rowptr[i0 + lane] : 0;
    int p0 = __shfl(r, n, 64);
    int p1 = __shfl(r, n + 1, 64);
    float f[8] = {0,0,0,0,0,0,0,0};
    for (int p = p0 + j; p < p1; p += 8) {
      int c = col[p];
      uint4 wv = yp[c];
      ACCW(wv);
    }
    if (((p1 - p0) & 7) == j) {           // self-loop: exactly one lane per node
      uint4 wv = yp[i0 + n];
      ACCW(wv);
    }
#pragma unroll
    for (int k = 0; k < 8; ++k) {
      float v = f[k];
      v += __shfl_xor(v, 1, 64);
      v += __shfl_xor(v, 2, 64);
      v += __shfl_xor(v, 4, 64);
      f[k] = v;
    }
    if (j == 0) {
      int i = i0 + n;
      float di = dinv[i];
      float vo[8];
#pragma unroll
      for (int k = 0; k < 8; ++k) {
        float v = di * f[k] + bv[k];
        if (PR && v < 0.f) v *= av[k];
        vo[k] = v;
        sa[k] += v; qa[k] += v * v;
      }
      if (HB) {
        uint4 u;
        u.x = packbf2(vo[0], vo[1]); u.y = packbf2(vo[2], vo[3]);
        u.z = packbf2(vo[4], vo[5]); u.w = packbf2(vo[6], vo[7]);
        hb4[(long)i * 8 + s] = u;
      } else {
        *(float4*)(h + (long)i * 64 + 8 * s)     = make_float4(vo[0], vo[1], vo[2], vo[3]);
        *(float4*)(h + (long)i * 64 + 8 * s + 4) = make_float4(vo[4], vo[5], vo[6], vo[7]);
      }
    }
  }
  if (j == 0) {
#pragma unroll
    for (int k = 0; k < 8; ++k) { atomicAdd(&ssum[k], sa[k]); atomicAdd(&ssq[k], qa[k]); }
  }
  __syncthreads();
  if (t < 8) {
    atomicAdd(&sums[8 * s + t], ssum[t]);
    atomicAdd(&sumsq[8 * s + t], ssq[t]);
  }
}

// ---------------- Set2Set: fused attention pass (bf16 h, 8-lane groups) ----------------
__global__ __launch_bounds__(256) void k_att(const uint4* __restrict__ hb4, const float* __restrict__ sm,
                                             float* __restrict__ part) {
  __shared__ float gm[32], gz[32], gr[32][64];
  int t = threadIdx.x;
  int grp = t >> 3, l7 = t & 7;
  float hvr[8];
#pragma unroll
  for (int k = 0; k < 8; ++k) hvr[k] = sm[SM_HV + 8 * l7 + k];
  float eoff = sm[SM_EOFF];
  float m = -3.4e38f, z = 0.f;
  float r[8] = {0,0,0,0,0,0,0,0};
  int ngrp = gridDim.x * 32;
  for (int i = blockIdx.x * 32 + grp; i < NN; i += ngrp) {
    uint4 hw = hb4[(long)i * 8 + l7];
    float hx[8] = { bflo(hw.x), bfhi(hw.x), bflo(hw.y), bfhi(hw.y),
                    bflo(hw.z), bfhi(hw.z), bflo(hw.w), bfhi(hw.w) };
    float dot = 0.f;
#pragma unroll
    for (int k = 0; k < 8; ++k) dot += hx[k] * hvr[k];
    dot += __shfl_xor(dot, 1, 64);
    dot += __shfl_xor(dot, 2, 64);
    dot += __shfl_xor(dot, 4, 64);
    float e = dot + eoff;
    float mn = fmaxf(m, e);
    float sc = expf(m - mn);
    float pb = expf(e - mn);
    z = z * sc + pb;
#pragma unroll
    for (int k = 0; k < 8; ++k) r[k] = r[k] * sc + pb * hx[k];
    m = mn;
  }
#pragma unroll
  for (int k = 0; k < 8; ++k) gr[grp][8 * l7 + k] = r[k];
  if (l7 == 0) { gm[grp] = m; gz[grp] = z; }
  __syncthreads();
  if (t < 64) {
    float mb = gm[0];
#pragma unroll
    for (int k = 1; k < 32; ++k) mb = fmaxf(mb, gm[k]);
    float rb = 0.f, zb = 0.f;
#pragma unroll 8
    for (int k = 0; k < 32; ++k) {
      float scl = expf(gm[k] - mb);
      rb += gr[k][t] * scl;
      zb += gz[k] * scl;
    }
    part[blockIdx.x * 68 + t] = rb;
    if (t == 0) { part[blockIdx.x * 68 + 64] = mb; part[blockIdx.x * 68 + 65] = zb; }
  }
}

// ---------------- Set2Set finish: reduce partials -> q_star -> LSTM(next) -> hv ----------------
// mode 0: boot (no reduce; LSTM from q*=0), 1: mid step, 2: final (write out, no LSTM)
__global__ __launch_bounds__(256) void k_attfin(const float* __restrict__ part,
                                                const float* __restrict__ gw, const float* __restrict__ gb,
                                                const float* __restrict__ gms,
                                                const float* __restrict__ sums, const float* __restrict__ sumsq,
                                                const float* __restrict__ Wih, const float* __restrict__ Whh,
                                                const float* __restrict__ bih, const float* __restrict__ bhh,
                                                float* __restrict__ sm, float* __restrict__ out, int mode) {
  __shared__ float hsL[64], cL[64], qsL[128], gL[256], red[256], sf[NB_ATT], rr4[4][64];
  int t = threadIdx.x, lane = t & 63, w = t >> 6;
  if (t < 64) { hsL[t] = sm[SM_HS + t]; cL[t] = sm[SM_C + t]; }
  __syncthreads();
  if (mode > 0) {
    float mv0 = part[t * 68 + 64];
    float mv1 = part[(t + 256) * 68 + 64];
    red[t] = fmaxf(mv0, mv1); __syncthreads();
    for (int s = 128; s; s >>= 1) { if (t < s) red[t] = fmaxf(red[t], red[t + s]); __syncthreads(); }
    float mg = red[0];
    __syncthreads();
    float sc0 = expf(mv0 - mg), sc1 = expf(mv1 - mg);
    sf[t] = sc0; sf[t + 256] = sc1;
    red[t] = part[t * 68 + 65] * sc0 + part[(t + 256) * 68 + 65] * sc1;
    __syncthreads();
    for (int s = 128; s; s >>= 1) { if (t < s) red[t] += red[t + s]; __syncthreads(); }
    float zg = red[0];
    __syncthreads();
    float racc = 0.f;
#pragma unroll 8
    for (int jx = 0; jx < 128; ++jx) {
      int bk = 4 * jx + w;
      racc += part[bk * 68 + lane] * sf[bk];
    }
    rr4[w][lane] = racc;
    __syncthreads();
    if (t < 64) {
      float rg = rr4[0][t] + rr4[1][t] + rr4[2][t] + rr4[3][t];
      float sc, sh;
      gn_affine(t, gw, gb, gms, sums, sumsq, sc, sh);
      float rr = sc * (rg / zg) + sh;
      qsL[t] = hsL[t]; qsL[64 + t] = rr;
      if (mode == 2) { out[t] = hsL[t]; out[64 + t] = rr; }
    }
  } else {
    if (t < 64) { qsL[t] = 0.f; qsL[64 + t] = 0.f; hsL[t] = 0.f; cL[t] = 0.f; }
  }
  __syncthreads();
  if (mode == 2) return;
  float g = bih[t] + bhh[t];
#pragma unroll 16
  for (int k = 0; k < 128; ++k) g += qsL[k] * Wih[t * 128 + k];
#pragma unroll 16
  for (int k = 0; k < 64; ++k) g += hsL[k] * Whh[t * 64 + k];
  gL[t] = g;
  __syncthreads();
  if (t < 64) {
    float ig = 1.f / (1.f + expf(-gL[t]));
    float fg = 1.f / (1.f + expf(-gL[64 + t]));
    float gg = tanhf(gL[128 + t]);
    float og = 1.f / (1.f + expf(-gL[192 + t]));
    float c = fg * cL[t] + ig * gg;
    float hsn = og * tanhf(c);
    sm[SM_C + t] = c;
    sm[SM_HS + t] = hsn;
    float sc, sh;
    gn_affine(t, gw, gb, gms, sums, sumsq, sc, sh);
    sm[SM_HV + t] = sc * hsn;
    red[t] = sh * hsn;
  }
  __syncthreads();
  if (t == 0) {
    float s = 0.f;
    for (int k = 0; k < 64; ++k) s += red[k];
    sm[SM_EOFF] = s;
  }
}

extern "C" void kernel_launch(void* const* d_in, const int* in_sizes, int n_in,
                              void* d_out, int out_size, void* d_ws, size_t ws_size,
                              hipStream_t stream) {
  const float* x     = (const float*)d_in[0];
  const float* gn0_w = (const float*)d_in[1];
  const float* gn0_b = (const float*)d_in[2];
  const float* gn0_ms= (const float*)d_in[3];
  const float* W1    = (const float*)d_in[4];
  const float* b1    = (const float*)d_in[5];
  const float* a1    = (const float*)d_in[6];
  const float* gn1_w = (const float*)d_in[7];
  const float* gn1_b = (const float*)d_in[8];
  const float* gn1_ms= (const float*)d_in[9];
  const float* W2    = (const float*)d_in[10];
  const float* b2    = (const float*)d_in[11];
  const float* a2    = (const float*)d_in[12];
  const float* gn2_w = (const float*)d_in[13];
  const float* gn2_b = (const float*)d_in[14];
  const float* gn2_ms= (const float*)d_in[15];
  const float* W3    = (const float*)d_in[16];
  const float* b3    = (const float*)d_in[17];
  const float* gn3_w = (const float*)d_in[18];
  const float* gn3_b = (const float*)d_in[19];
  const float* gn3_ms= (const float*)d_in[20];
  const float* Wih   = (const float*)d_in[21];
  const float* Whh   = (const float*)d_in[22];
  const float* bih   = (const float*)d_in[23];
  const float* bhh   = (const float*)d_in[24];
  const int*   eidx  = (const int*)d_in[25];
  const int* esrc = eidx;
  const int* edst = eidx + NE;

  float* sm   = (float*)d_ws;
  int* gcursor= (int*)(sm + SM_GCUR);          // 392 ints, zeroed by memset (counts)
  float* gpart= sm + SM_GPART;                 // 782*8, fully written each call
  float* dinv = sm + OFF_DINV;
  float* h    = sm + OFF_H;
  unsigned* stage = (unsigned*)(sm + OFF_H);   // aliases h; dead before first gather
  uint4* hb4  = (uint4*)(sm + OFF_H);          // aliases h; written only after h is dead
  unsigned* y32 = (unsigned*)(sm + OFF_Y32);
  const uint4* y4 = (const uint4*)y32;
  float* part = sm + OFF_PART;
  int* col    = (int*)(sm + OFF_INT);          // NE
  int* rowptr = col + NE;                      // NPAD (NN+1)
  int* boff   = rowptr + NPAD;                 // NBUK+1
  float* out  = (float*)d_out;

  hipMemsetAsync(sm, 0, SM_ZEND * sizeof(float), stream);

  // CSR build (gn0 stats via block partials, reduced in k_bscan)
  k_bin<<<NTILES, 256, 0, stream>>>(esrc, edst, x, gcursor, stage, gpart);
  k_bscan<<<1, 512, 0, stream>>>(gcursor, boff, rowptr, gpart,
                                 sm + SM_SUMS(0), sm + SM_SUMSQ(0));
  k_bsort<<<NBUK, 256, 0, stream>>>(stage, boff, col, rowptr, dinv);

  // layer 1
  k_mm<4><<<1024, 256, 0, stream>>>(x, W1, gn0_w, gn0_b, gn0_ms,
                                    sm + SM_SUMS(0), sm + SM_SUMSQ(0), dinv, y32);
  k_gather_fin<true, false><<<2048, 256, 0, stream>>>(y4, rowptr, col, dinv, b1, a1, h, nullptr,
                                                      sm + SM_SUMS(1), sm + SM_SUMSQ(1));
  // layer 2
  k_mm<64><<<1024, 256, 0, stream>>>(h, W2, gn1_w, gn1_b, gn1_ms,
                                     sm + SM_SUMS(1), sm + SM_SUMSQ(1), dinv, y32);
  k_gather_fin<true, false><<<2048, 256, 0, stream>>>(y4, rowptr, col, dinv, b2, a2, h, nullptr,
                                                      sm + SM_SUMS(2), sm + SM_SUMSQ(2));
  // layer 3 (no prelu): writes bf16 h copy only
  k_mm<64><<<1024, 256, 0, stream>>>(h, W3, gn2_w, gn2_b, gn2_ms,
                                     sm + SM_SUMS(2), sm + SM_SUMSQ(2), dinv, y32);
  k_gather_fin<false, true><<<2048, 256, 0, stream>>>(y4, rowptr, col, dinv, b3, nullptr, nullptr, hb4,
                                                      sm + SM_SUMS(3), sm + SM_SUMSQ(3));

  // Set2Set: boot LSTM (q*=0) + hv, then 3 steps
  k_attfin<<<1, 256, 0, stream>>>(part, gn3_w, gn3_b, gn3_ms,
                                  sm + SM_SUMS(3), sm + SM_SUMSQ(3),
                                  Wih, Whh, bih, bhh, sm, nullptr, 0);
  for (int s = 0; s < 3; ++s) {
    k_att<<<NB_ATT, 256, 0, stream>>>(hb4, sm, part);
    k_attfin<<<1, 256, 0, stream>>>(part, gn3_w, gn3_b, gn3_ms,
                                    sm + SM_SUMS(3), sm + SM_SUMSQ(3),
                                    Wih, Whh, bih, bhh, sm,
                                    (s == 2) ? out : nullptr, (s == 2) ? 2 : 1);
  }
}

// Round 12
// 419.439 us; speedup vs baseline: 2.0802x; 1.0326x over previous
//
#include <hip/hip_runtime.h>

#define NN 100000
#define NE 1600000
#define HID 64
#define EPSV 1e-5f
#define NB_ATT 512
#define NGRP 12500               // NN/8 node-groups for slice gather

// bucketed CSR build
#define NBUK 391                 // ceil(100000/256), bucket = dst>>8
#define BCAP 4608                // slots per bucket (lambda~4092, +8 sigma)
#define BTILE 2048               // edges per bin tile
#define NTILES 782               // ceil(NE/BTILE)

// ---------- small scratch layout (float indices into ws) ----------
#define SM_SUMS(l)  ((l)*128)
#define SM_SUMSQ(l) ((l)*128 + 64)
#define SM_HS       512
#define SM_C        576
#define SM_HV       768          // 64 floats
#define SM_EOFF     832
#define SM_GCUR     1024         // 392 ints (zeroed by memset)
#define SM_ZEND     1424         // memset covers [0, SM_ZEND)
#define SM_GPART    1424         // 782*8 floats, all written before read (no zero needed)

// big buffers (float offsets)
#define NPAD        100352L
#define OFF_DINV    7684L
#define OFF_H       (OFF_DINV + NPAD)       // 6.4M floats; stage/hb alias; h is PLANE-major [8][NN][8f]
#define OFF_Y32     (OFF_H + 6400000L)      // 3.2M uints (bf16x2), PLANE-major: 8 x NN x 16B
#define OFF_PART    (OFF_Y32 + 3200000L)    // NB_ATT*68
#define OFF_INT     (OFF_PART + 69632L)

static __device__ __forceinline__ unsigned bf16rne(float f) {
  unsigned u = __float_as_uint(f);
  return (u + 0x7fffu + ((u >> 16) & 1u)) >> 16;
}
static __device__ __forceinline__ unsigned packbf2(float lo, float hi) {
  return bf16rne(lo) | (bf16rne(hi) << 16);
}
static __device__ __forceinline__ float bflo(unsigned w) { return __uint_as_float(w << 16); }
static __device__ __forceinline__ float bfhi(unsigned w) { return __uint_as_float(w & 0xffff0000u); }

// GraphNorm affine from accumulated sums: gn(x) = sc*x + sh  (per feature j)
static __device__ __forceinline__ void gn_affine(int j, const float* w, const float* b,
                                                 const float* ms, const float* sums,
                                                 const float* sumsq, float& sc, float& sh) {
  const float invn = 1.0f / (float)NN;
  float mean = sums[j] * invn;
  float ex2  = sumsq[j] * invn;
  float m    = ms[j];
  float var  = ex2 - m * mean * mean * (2.0f - m);
  sc = w[j] * rsqrtf(var + EPSV);
  sh = b[j] - sc * m * mean;
}

// ---------------- pass 1: bin edges into per-bucket staging + gn0 block partials ----------------
__global__ __launch_bounds__(256) void k_bin(const int* __restrict__ src, const int* __restrict__ dst,
                                             const float* __restrict__ x,
                                             int* __restrict__ gcursor, unsigned* __restrict__ stage,
                                             float* __restrict__ gpart) {
  __shared__ int hist[NBUK], base[NBUK];
  __shared__ float gred[4][8];
  int t = threadIdx.x, lane = t & 63, w = t >> 6;
  long tile0 = (long)blockIdx.x * BTILE;
  for (int b = t; b < NBUK; b += 256) hist[b] = 0;
  __syncthreads();
  unsigned v[8]; int bk[8];
#pragma unroll
  for (int k = 0; k < 8; ++k) {
    long e = tile0 + k * 256 + t;
    if (e < NE) {
      int d = dst[e], s = src[e];
      bk[k] = d >> 8;
      v[k] = ((unsigned)(d & 255) << 24) | (unsigned)s;
      atomicAdd(&hist[bk[k]], 1);
    } else bk[k] = -1;
  }
  __syncthreads();
  for (int b = t; b < NBUK; b += 256) {
    int c = hist[b];
    base[b] = c ? atomicAdd(&gcursor[b], c) : 0;
    hist[b] = 0;
  }
  __syncthreads();
#pragma unroll
  for (int k = 0; k < 8; ++k) {
    if (bk[k] >= 0) {
      int bkk = bk[k];
      int off = atomicAdd(&hist[bkk], 1);
      stage[(long)bkk * BCAP + base[bkk] + off] = v[k];
    }
  }
  // gn0 stats over x -> per-block partial (no atomics)
  const float4* x4 = (const float4*)x;
  float4 s4 = make_float4(0.f, 0.f, 0.f, 0.f);
  float4 q4 = make_float4(0.f, 0.f, 0.f, 0.f);
  int stride = gridDim.x * 256;
  for (int i = blockIdx.x * 256 + t; i < NN; i += stride) {
    float4 xv = x4[i];
    s4.x += xv.x; s4.y += xv.y; s4.z += xv.z; s4.w += xv.w;
    q4.x += xv.x * xv.x; q4.y += xv.y * xv.y; q4.z += xv.z * xv.z; q4.w += xv.w * xv.w;
  }
#pragma unroll
  for (int off = 32; off; off >>= 1) {
    s4.x += __shfl_xor(s4.x, off, 64); s4.y += __shfl_xor(s4.y, off, 64);
    s4.z += __shfl_xor(s4.z, off, 64); s4.w += __shfl_xor(s4.w, off, 64);
    q4.x += __shfl_xor(q4.x, off, 64); q4.y += __shfl_xor(q4.y, off, 64);
    q4.z += __shfl_xor(q4.z, off, 64); q4.w += __shfl_xor(q4.w, off, 64);
  }
  if (lane == 0) {
    gred[w][0] = s4.x; gred[w][1] = s4.y; gred[w][2] = s4.z; gred[w][3] = s4.w;
    gred[w][4] = q4.x; gred[w][5] = q4.y; gred[w][6] = q4.z; gred[w][7] = q4.w;
  }
  __syncthreads();
  if (t < 8) gpart[blockIdx.x * 8 + t] = gred[0][t] + gred[1][t] + gred[2][t] + gred[3][t];
}

// ---------------- pass 1b: scan bucket counts -> boff; reduce gn0 partials ----------------
__global__ __launch_bounds__(512) void k_bscan(const int* __restrict__ gcursor,
                                               int* __restrict__ boff, int* __restrict__ rowptr,
                                               const float* __restrict__ gpart,
                                               float* __restrict__ sums0, float* __restrict__ sumsq0) {
  __shared__ int ws[8];
  __shared__ float gl[64][8];
  int t = threadIdx.x, lane = t & 63;
  int c = (t < NBUK) ? gcursor[t] : 0;
  int incl = c;
#pragma unroll
  for (int off = 1; off < 64; off <<= 1) {
    int u = __shfl_up(incl, off, 64);
    if (lane >= off) incl += u;
  }
  if (lane == 63) ws[t >> 6] = incl;
  __syncthreads();
  if (t == 0) {
    int s = 0;
#pragma unroll
    for (int w = 0; w < 8; ++w) { int tv = ws[w]; ws[w] = s; s += tv; }
  }
  __syncthreads();
  if (t < NBUK) boff[t] = incl - c + ws[t >> 6];
  if (t == 0) { boff[NBUK] = NE; rowptr[NN] = NE; }
  // gn0 partial reduce: 782 x 8 -> 8
  float acc = 0.f;
  int f = t & 7, r = t >> 3;            // 64 row-groups
  for (int i = r; i < NTILES; i += 64) acc += gpart[i * 8 + f];
  gl[r][f] = acc;
  __syncthreads();
  if (t < 8) {
    float s = 0.f;
#pragma unroll 16
    for (int rr = 0; rr < 64; ++rr) s += gl[rr][t];
    if (t < 4) sums0[t] = s;
    else sumsq0[t - 4] = s;
  }
}

// ---------------- pass 2: per-bucket counting sort -> col, rowptr, dinv ----------------
__global__ __launch_bounds__(256) void k_bsort(const unsigned* __restrict__ stage,
                                               const int* __restrict__ boff,
                                               int* __restrict__ col, int* __restrict__ rowptr,
                                               float* __restrict__ dinv) {
  __shared__ int hist[256], cur[256];
  __shared__ int ws[4];
  int b = blockIdx.x;
  int t = threadIdx.x, lane = t & 63;
  long sb = (long)b * BCAP;
  int b0 = boff[b], cb = boff[b + 1] - b0;
  hist[t] = 0;
  __syncthreads();
  for (int j = t; j < cb; j += 256)
    atomicAdd(&hist[stage[sb + j] >> 24], 1);
  __syncthreads();
  int c = hist[t];
  int incl = c;
#pragma unroll
  for (int off = 1; off < 64; off <<= 1) {
    int u = __shfl_up(incl, off, 64);
    if (lane >= off) incl += u;
  }
  if (lane == 63) ws[t >> 6] = incl;
  __syncthreads();
  int woff = 0;
  if (t >= 64) woff += ws[0];
  if (t >= 128) woff += ws[1];
  if (t >= 192) woff += ws[2];
  int gbase = b0 + (incl - c) + woff;
  int node = b * 256 + t;
  if (node < NN) {
    rowptr[node] = gbase;
    dinv[node] = rsqrtf((float)c + 1.0f);
  }
  cur[t] = gbase;
  __syncthreads();
  for (int j = t; j < cb; j += 256) {
    unsigned v = stage[sb + j];
    int pos = atomicAdd(&cur[v >> 24], 1);
    col[pos] = (int)(v & 0xffffffu);
  }
}

// ---------------- fused GraphNorm-apply + matmul + dinv prescale -> bf16 y (PLANE-major) ----------------
// h input (D==64) is PLANE-major fp32 [8][NN][8]; x input (D==4) is node-major.
template <int D>
__global__ __launch_bounds__(256) void k_mm(const float* __restrict__ hin, const float* __restrict__ W,
                                            const float* __restrict__ gw, const float* __restrict__ gb,
                                            const float* __restrict__ gms,
                                            const float* __restrict__ sums, const float* __restrict__ sumsq,
                                            const float* __restrict__ dinv,
                                            unsigned* __restrict__ y32) {
  __shared__ float4 Ws4[D][16];
  __shared__ float4 woff4[16];
  __shared__ float scale[D], shift[D];
  __shared__ float hl[16][68];      // stride 68: 16B-aligned rows, bank-shift 4
  int t = threadIdx.x;
  if (t < D) {
    float sc, sh;
    gn_affine(t, gw, gb, gms, sums, sumsq, sc, sh);
    scale[t] = sc; shift[t] = sh;
  }
  __syncthreads();
  for (int idx = t; idx < D * 64; idx += 256) {
    int k = idx >> 6;
    ((float*)Ws4)[idx] = scale[k] * W[idx];
  }
  __syncthreads();
  if (t < 64) {
    float o = 0.f;
#pragma unroll
    for (int k = 0; k < D; ++k) o += shift[k] * W[k * 64 + t];
    ((float*)woff4)[t] = o;
  }
  __syncthreads();

  int row = t >> 4, cg = t & 15;
  const int nG = NN / 16;  // 6250, exact
  for (int g = blockIdx.x; g < nG; g += gridDim.x) {
    int node = g * 16 + row;
    if (D == 64) {
      // planar read: plane cg>>1, half cg&1
      *(float4*)&hl[row][cg * 4] =
        *(const float4*)(hin + ((long)(cg >> 1) * NN + node) * 8 + (cg & 1) * 4);
    } else {
      if (t < 64) hl[t >> 2][t & 3] = hin[g * 64 + t];
    }
    __syncthreads();
    float4 acc = woff4[cg];
#pragma unroll
    for (int k = 0; k < D; ++k) {
      float hk = hl[row][k];
      float4 w4 = Ws4[k][cg];
      acc.x += hk * w4.x; acc.y += hk * w4.y;
      acc.z += hk * w4.z; acc.w += hk * w4.w;
    }
    float di = dinv[node];
    uint2 u;
    u.x = packbf2(di * acc.x, di * acc.y);
    u.y = packbf2(di * acc.z, di * acc.w);
    // y plane-major: plane = cg>>1, half = cg&1
    *(uint2*)(y32 + ((long)(cg >> 1) * NN + node) * 4 + (cg & 1) * 2) = u;
    __syncthreads();
  }
}

// ---------------- XCD-sliced CSR gather (plane-major y; plane-major h/hb output) ----------------
#define ACCW(WV) { f[0]+=bflo(WV.x); f[1]+=bfhi(WV.x); f[2]+=bflo(WV.y); f[3]+=bfhi(WV.y); \
                   f[4]+=bflo(WV.z); f[5]+=bfhi(WV.z); f[6]+=bflo(WV.w); f[7]+=bfhi(WV.w); }

template <bool PR, bool HB>
__global__ __launch_bounds__(256) void k_gather_fin(const uint4* __restrict__ y4x,
                                                    const int* __restrict__ rowptr, const int* __restrict__ col,
                                                    const float* __restrict__ dinv,
                                                    const float* __restrict__ b, const float* __restrict__ a,
                                                    float* __restrict__ hp, uint4* __restrict__ hb4p,
                                                    float* __restrict__ sums, float* __restrict__ sumsq) {
  __shared__ float ssum[8], ssq[8];
  int t = threadIdx.x, lane = t & 63, w = t >> 6;
  int n = lane >> 3, j = lane & 7;
  int s = blockIdx.x & 7;
  const uint4* yp = y4x + (long)s * NN;   // this slice's plane
  if (t < 8) { ssum[t] = 0.f; ssq[t] = 0.f; }
  __syncthreads();
  float bv[8], av[8];
#pragma unroll
  for (int k = 0; k < 8; ++k) {
    bv[k] = b[8 * s + k];
    av[k] = PR ? a[8 * s + k] : 1.f;
  }
  float sa[8] = {0,0,0,0,0,0,0,0}, qa[8] = {0,0,0,0,0,0,0,0};
  int gstride = (gridDim.x >> 3) * 4;
  int g = (blockIdx.x >> 3) * 4 + w;
  int rcur = 0;
  if (g < NGRP && lane < 9) rcur = rowptr[g * 8 + lane];
  while (g < NGRP) {
    int gn = g + gstride;
    int rn = 0;
    if (gn < NGRP && lane < 9) rn = rowptr[gn * 8 + lane];   // prefetch next group
    int i0 = g * 8;
    int p0 = __shfl(rcur, n, 64);
    int p1 = __shfl(rcur, n + 1, 64);
    float f[8] = {0,0,0,0,0,0,0,0};
    int p = p0 + j;
    // 2-edge unroll: 2 independent col loads -> 2 independent y loads in flight
    for (; p + 8 < p1; p += 16) {
      int c0 = col[p], c1 = col[p + 8];
      uint4 wa = yp[c0];
      uint4 wb = yp[c1];
      ACCW(wa); ACCW(wb);
    }
    if (p < p1) {
      uint4 wa = yp[col[p]];
      ACCW(wa);
    }
    if (((p1 - p0) & 7) == j) {           // self-loop: exactly one lane per node
      uint4 wa = yp[i0 + n];
      ACCW(wa);
    }
#pragma unroll
    for (int k = 0; k < 8; ++k) {
      float v = f[k];
      v += __shfl_xor(v, 1, 64);
      v += __shfl_xor(v, 2, 64);
      v += __shfl_xor(v, 4, 64);
      f[k] = v;
    }
    if (j == 0) {
      int i = i0 + n;
      float di = dinv[i];
      float vo[8];
#pragma unroll
      for (int k = 0; k < 8; ++k) {
        float v = di * f[k] + bv[k];
        if (PR && v < 0.f) v *= av[k];
        vo[k] = v;
        sa[k] += v; qa[k] += v * v;
      }
      if (HB) {
        uint4 u;
        u.x = packbf2(vo[0], vo[1]); u.y = packbf2(vo[2], vo[3]);
        u.z = packbf2(vo[4], vo[5]); u.w = packbf2(vo[6], vo[7]);
        hb4p[(long)s * NN + i] = u;                       // plane-major bf16
      } else {
        float* hd = hp + ((long)s * NN + i) * 8;          // plane-major fp32
        *(float4*)hd       = make_float4(vo[0], vo[1], vo[2], vo[3]);
        *(float4*)(hd + 4) = make_float4(vo[4], vo[5], vo[6], vo[7]);
      }
    }
    g = gn; rcur = rn;
  }
  if (j == 0) {
#pragma unroll
    for (int k = 0; k < 8; ++k) { atomicAdd(&ssum[k], sa[k]); atomicAdd(&ssq[k], qa[k]); }
  }
  __syncthreads();
  if (t < 8) {
    atomicAdd(&sums[8 * s + t], ssum[t]);
    atomicAdd(&sumsq[8 * s + t], ssq[t]);
  }
}

// ---------------- Set2Set: fused attention pass (plane-major bf16 h) ----------------
// thread = (plane p = t>>5, node nn = t&31); chunk = 32 nodes; NN % 32 == 0.
__global__ __launch_bounds__(256) void k_att(const uint4* __restrict__ hb4p, const float* __restrict__ sm,
                                             float* __restrict__ part) {
  __shared__ float ldot[2][8][32];
  __shared__ float lr[8][32][8];
  __shared__ float lz[32];
  int t = threadIdx.x;
  int p = t >> 5, nn = t & 31;
  float hvr[8];
#pragma unroll
  for (int k = 0; k < 8; ++k) hvr[k] = sm[SM_HV + 8 * p + k];
  float eoff = sm[SM_EOFF];
  float m = -3.4e38f, z = 0.f;
  float r[8] = {0,0,0,0,0,0,0,0};
  int buf = 0;
  int stride = gridDim.x * 32;
  for (int i0 = blockIdx.x * 32; i0 < NN; i0 += stride) {
    int i = i0 + nn;
    uint4 hw = hb4p[(long)p * NN + i];
    float hx[8] = { bflo(hw.x), bfhi(hw.x), bflo(hw.y), bfhi(hw.y),
                    bflo(hw.z), bfhi(hw.z), bflo(hw.w), bfhi(hw.w) };
    float d = 0.f;
#pragma unroll
    for (int k = 0; k < 8; ++k) d += hx[k] * hvr[k];
    ldot[buf][p][nn] = d;
    __syncthreads();
    float e = eoff;
#pragma unroll
    for (int pp = 0; pp < 8; ++pp) e += ldot[buf][pp][nn];
    float mn = fmaxf(m, e);
    float sc = expf(m - mn);
    float pb = expf(e - mn);
    z = z * sc + pb;
#pragma unroll
    for (int k = 0; k < 8; ++k) r[k] = r[k] * sc + pb * hx[k];
    m = mn;
    buf ^= 1;
  }
  // block combine: m depends only on nn (identical across p and waves)
  float mb = m;
#pragma unroll
  for (int off = 16; off; off >>= 1) mb = fmaxf(mb, __shfl_xor(mb, off, 64));
  float scl = expf(m - mb);
#pragma unroll
  for (int k = 0; k < 8; ++k) lr[p][nn][k] = r[k] * scl;
  if (p == 0) lz[nn] = z * scl;
  __syncthreads();
  if (t < 64) {
    int pp = t >> 3, k = t & 7;
    float rb = 0.f;
#pragma unroll 8
    for (int n2 = 0; n2 < 32; ++n2) rb += lr[pp][n2][k];
    part[blockIdx.x * 68 + t] = rb;
  }
  if (t == 0) {
    float zb = 0.f;
#pragma unroll 8
    for (int n2 = 0; n2 < 32; ++n2) zb += lz[n2];
    part[blockIdx.x * 68 + 64] = mb;
    part[blockIdx.x * 68 + 65] = zb;
  }
}

// ---------------- Set2Set finish: reduce partials -> q_star -> LSTM(next) -> hv ----------------
// mode 0: boot (no reduce; LSTM from q*=0), 1: mid step, 2: final (write out, no LSTM)
__global__ __launch_bounds__(256) void k_attfin(const float* __restrict__ part,
                                                const float* __restrict__ gw, const float* __restrict__ gb,
                                                const float* __restrict__ gms,
                                                const float* __restrict__ sums, const float* __restrict__ sumsq,
                                                const float* __restrict__ Wih, const float* __restrict__ Whh,
                                                const float* __restrict__ bih, const float* __restrict__ bhh,
                                                float* __restrict__ sm, float* __restrict__ out, int mode) {
  __shared__ float hsL[64], cL[64], qsL[128], gL[256], red[256], sf[NB_ATT], rr4[4][64];
  int t = threadIdx.x, lane = t & 63, w = t >> 6;
  if (t < 64) { hsL[t] = sm[SM_HS + t]; cL[t] = sm[SM_C + t]; }
  __syncthreads();
  if (mode > 0) {
    float mv0 = part[t * 68 + 64];
    float mv1 = part[(t + 256) * 68 + 64];
    red[t] = fmaxf(mv0, mv1); __syncthreads();
    for (int s = 128; s; s >>= 1) { if (t < s) red[t] = fmaxf(red[t], red[t + s]); __syncthreads(); }
    float mg = red[0];
    __syncthreads();
    float sc0 = expf(mv0 - mg), sc1 = expf(mv1 - mg);
    sf[t] = sc0; sf[t + 256] = sc1;
    red[t] = part[t * 68 + 65] * sc0 + part[(t + 256) * 68 + 65] * sc1;
    __syncthreads();
    for (int s = 128; s; s >>= 1) { if (t < s) red[t] += red[t + s]; __syncthreads(); }
    float zg = red[0];
    __syncthreads();
    float racc = 0.f;
#pragma unroll 8
    for (int jx = 0; jx < 128; ++jx) {
      int bk = 4 * jx + w;
      racc += part[bk * 68 + lane] * sf[bk];
    }
    rr4[w][lane] = racc;
    __syncthreads();
    if (t < 64) {
      float rg = rr4[0][t] + rr4[1][t] + rr4[2][t] + rr4[3][t];
      float sc, sh;
      gn_affine(t, gw, gb, gms, sums, sumsq, sc, sh);
      float rr = sc * (rg / zg) + sh;
      qsL[t] = hsL[t]; qsL[64 + t] = rr;
      if (mode == 2) { out[t] = hsL[t]; out[64 + t] = rr; }
    }
  } else {
    if (t < 64) { qsL[t] = 0.f; qsL[64 + t] = 0.f; hsL[t] = 0.f; cL[t] = 0.f; }
  }
  __syncthreads();
  if (mode == 2) return;
  float g = bih[t] + bhh[t];
#pragma unroll 16
  for (int k = 0; k < 128; ++k) g += qsL[k] * Wih[t * 128 + k];
#pragma unroll 16
  for (int k = 0; k < 64; ++k) g += hsL[k] * Whh[t * 64 + k];
  gL[t] = g;
  __syncthreads();
  if (t < 64) {
    float ig = 1.f / (1.f + expf(-gL[t]));
    float fg = 1.f / (1.f + expf(-gL[64 + t]));
    float gg = tanhf(gL[128 + t]);
    float og = 1.f / (1.f + expf(-gL[192 + t]));
    float c = fg * cL[t] + ig * gg;
    float hsn = og * tanhf(c);
    sm[SM_C + t] = c;
    sm[SM_HS + t] = hsn;
    float sc, sh;
    gn_affine(t, gw, gb, gms, sums, sumsq, sc, sh);
    sm[SM_HV + t] = sc * hsn;
    red[t] = sh * hsn;
  }
  __syncthreads();
  if (t == 0) {
    float s = 0.f;
    for (int k = 0; k < 64; ++k) s += red[k];
    sm[SM_EOFF] = s;
  }
}

extern "C" void kernel_launch(void* const* d_in, const int* in_sizes, int n_in,
                              void* d_out, int out_size, void* d_ws, size_t ws_size,
                              hipStream_t stream) {
  const float* x     = (const float*)d_in[0];
  const float* gn0_w = (const float*)d_in[1];
  const float* gn0_b = (const float*)d_in[2];
  const float* gn0_ms= (const float*)d_in[3];
  const float* W1    = (const float*)d_in[4];
  const float* b1    = (const float*)d_in[5];
  const float* a1    = (const float*)d_in[6];
  const float* gn1_w = (const float*)d_in[7];
  const float* gn1_b = (const float*)d_in[8];
  const float* gn1_ms= (const float*)d_in[9];
  const float* W2    = (const float*)d_in[10];
  const float* b2    = (const float*)d_in[11];
  const float* a2    = (const float*)d_in[12];
  const float* gn2_w = (const float*)d_in[13];
  const float* gn2_b = (const float*)d_in[14];
  const float* gn2_ms= (const float*)d_in[15];
  const float* W3    = (const float*)d_in[16];
  const float* b3    = (const float*)d_in[17];
  const float* gn3_w = (const float*)d_in[18];
  const float* gn3_b = (const float*)d_in[19];
  const float* gn3_ms= (const float*)d_in[20];
  const float* Wih   = (const float*)d_in[21];
  const float* Whh   = (const float*)d_in[22];
  const float* bih   = (const float*)d_in[23];
  const float* bhh   = (const float*)d_in[24];
  const int*   eidx  = (const int*)d_in[25];
  const int* esrc = eidx;
  const int* edst = eidx + NE;

  float* sm   = (float*)d_ws;
  int* gcursor= (int*)(sm + SM_GCUR);          // 392 ints, zeroed by memset (counts)
  float* gpart= sm + SM_GPART;                 // 782*8, fully written each call
  float* dinv = sm + OFF_DINV;
  float* h    = sm + OFF_H;                    // plane-major fp32 [8][NN][8]
  unsigned* stage = (unsigned*)(sm + OFF_H);   // aliases h; dead before first gather
  uint4* hb4  = (uint4*)(sm + OFF_H);          // aliases h; plane-major bf16 [8][NN]
  unsigned* y32 = (unsigned*)(sm + OFF_Y32);
  const uint4* y4 = (const uint4*)y32;
  float* part = sm + OFF_PART;
  int* col    = (int*)(sm + OFF_INT);          // NE
  int* rowptr = col + NE;                      // NPAD (NN+1)
  int* boff   = rowptr + NPAD;                 // NBUK+1
  float* out  = (float*)d_out;

  hipMemsetAsync(sm, 0, SM_ZEND * sizeof(float), stream);

  // CSR build (gn0 stats via block partials, reduced in k_bscan)
  k_bin<<<NTILES, 256, 0, stream>>>(esrc, edst, x, gcursor, stage, gpart);
  k_bscan<<<1, 512, 0, stream>>>(gcursor, boff, rowptr, gpart,
                                 sm + SM_SUMS(0), sm + SM_SUMSQ(0));
  k_bsort<<<NBUK, 256, 0, stream>>>(stage, boff, col, rowptr, dinv);

  // layer 1
  k_mm<4><<<1024, 256, 0, stream>>>(x, W1, gn0_w, gn0_b, gn0_ms,
                                    sm + SM_SUMS(0), sm + SM_SUMSQ(0), dinv, y32);
  k_gather_fin<true, false><<<2048, 256, 0, stream>>>(y4, rowptr, col, dinv, b1, a1, h, nullptr,
                                                      sm + SM_SUMS(1), sm + SM_SUMSQ(1));
  // layer 2
  k_mm<64><<<1024, 256, 0, stream>>>(h, W2, gn1_w, gn1_b, gn1_ms,
                                     sm + SM_SUMS(1), sm + SM_SUMSQ(1), dinv, y32);
  k_gather_fin<true, false><<<2048, 256, 0, stream>>>(y4, rowptr, col, dinv, b2, a2, h, nullptr,
                                                      sm + SM_SUMS(2), sm + SM_SUMSQ(2));
  // layer 3 (no prelu): writes plane-major bf16 h copy only
  k_mm<64><<<1024, 256, 0, stream>>>(h, W3, gn2_w, gn2_b, gn2_ms,
                                     sm + SM_SUMS(2), sm + SM_SUMSQ(2), dinv, y32);
  k_gather_fin<false, true><<<2048, 256, 0, stream>>>(y4, rowptr, col, dinv, b3, nullptr, nullptr, hb4,
                                                      sm + SM_SUMS(3), sm + SM_SUMSQ(3));

  // Set2Set: boot LSTM (q*=0) + hv, then 3 steps
  k_attfin<<<1, 256, 0, stream>>>(part, gn3_w, gn3_b, gn3_ms,
                                  sm + SM_SUMS(3), sm + SM_SUMSQ(3),
                                  Wih, Whh, bih, bhh, sm, nullptr, 0);
  for (int s = 0; s < 3; ++s) {
    k_att<<<NB_ATT, 256, 0, stream>>>(hb4, sm, part);
    k_attfin<<<1, 256, 0, stream>>>(part, gn3_w, gn3_b, gn3_ms,
                                    sm + SM_SUMS(3), sm + SM_SUMSQ(3),
                                    Wih, Whh, bih, bhh, sm,
                                    (s == 2) ? out : nullptr, (s == 2) ? 2 : 1);
  }
}